// Round 5
// baseline (2335.816 us; speedup 1.0000x reference)
//
#include <hip/hip_runtime.h>
#include <hip/hip_bf16.h>

#define DD 256
#define HH 8
#define DH 32
#define SS 512
#define MM 1024
#define BB 16
#define FF 1024
#define LL 6
#define VV 3000

typedef __bf16 bf16x8 __attribute__((ext_vector_type(8)));
typedef float  f32x4  __attribute__((ext_vector_type(4)));

// Wt layout offsets (elements). All matrices stored [N][K] bf16 hi/lo pairs.
#define W_QKV0 0u
#define W_SAO0 1179648u
#define W_CAQ0 1572864u
#define W_CKV0 1966080u
#define W_CAO0 2752512u
#define W_W10  3145728u
#define W_W20  4718592u
#define W_EMB0 6291456u
#define W_TOT  7061504u   // 6291456 + 3008*256

// Mixed-dtype load: bf==1 -> bf16, bf==0 -> fp32.
__device__ __forceinline__ float ldx(const void* p, size_t i, int bf) {
    if (bf) return __bfloat162float(((const __hip_bfloat16*)p)[i]);
    return ((const float*)p)[i];
}

// fp32 -> bf16 hi/lo split: v = hi + lo + O(2^-17 * v)
__device__ __forceinline__ void split1(float v, __bf16& h, __bf16& l) {
    h = (__bf16)v;
    l = (__bf16)(v - (float)h);
}

// LDS index with XOR chunk swizzle: tile [64 rows][64 el], 16B chunks,
// chunk c at row r lives at c ^ (r&7). Conflict-derivation: frag reads are
// 2 lanes/bank (free), staging writes at 8-cycle structural floor.
__device__ __forceinline__ int swzi(int row, int c) {
    return row * 64 + ((c ^ (row & 7)) << 3);
}

// dtype detector: writes 1 if buffer is bf16, 0 if fp32.
__global__ void detect_k(const unsigned int* __restrict__ w, int* __restrict__ flag) {
    int t = threadIdx.x;
    unsigned int v = w[t];
    int ok = 1;
#pragma unroll
    for (int h = 0; h < 2; ++h) {
        unsigned int hw = (v >> (16 * h)) & 0xFFFFu;
        unsigned int e = (hw >> 7) & 0xFFu;
        if (!((e >= 90u && e <= 140u) || (hw & 0x7FFFu) == 0u)) ok = 0;
    }
    __shared__ int allok;
    if (t == 0) allok = 1;
    __syncthreads();
    if (!ok) atomicAnd(&allok, 0);
    __syncthreads();
    if (t == 0) *flag = allok;
}

// One-time: transpose+split all layer weights into [N][K] bf16 hi/lo pairs.
__global__ __launch_bounds__(256)
void wsplit_k(const void* __restrict__ sa_qkv, const void* __restrict__ sa_o,
              const void* __restrict__ ca_q, const void* __restrict__ ca_kv,
              const void* __restrict__ ca_o, const void* __restrict__ w1,
              const void* __restrict__ w2,
              __bf16* __restrict__ Wh, __bf16* __restrict__ Wl,
              const int* __restrict__ flagp) {
    int bfw = *flagp;
    __shared__ float tile[64][65];
    int blk = blockIdx.x;
    int l = blk >> 8, r = blk & 255;
    const void* src; size_t soff, doff; int K_, N_, ti;
    if (r < 48)       { src = sa_qkv; int j = r >> 4; ti = r & 15;
                        soff = (size_t)(l * 3 + j) * 65536; doff = W_QKV0 + soff; K_ = 256; N_ = 256; }
    else if (r < 64)  { src = sa_o;  ti = r - 48;  soff = (size_t)l * 65536; doff = W_SAO0 + soff; K_ = 256; N_ = 256; }
    else if (r < 80)  { src = ca_q;  ti = r - 64;  soff = (size_t)l * 65536; doff = W_CAQ0 + soff; K_ = 256; N_ = 256; }
    else if (r < 112) { src = ca_kv; int j = (r - 80) >> 4; ti = (r - 80) & 15;
                        soff = (size_t)(l * 2 + j) * 65536; doff = W_CKV0 + soff; K_ = 256; N_ = 256; }
    else if (r < 128) { src = ca_o;  ti = r - 112; soff = (size_t)l * 65536; doff = W_CAO0 + soff; K_ = 256; N_ = 256; }
    else if (r < 192) { src = w1;    ti = r - 128; soff = (size_t)l * 262144; doff = W_W10 + soff; K_ = 256; N_ = 1024; }
    else              { src = w2;    ti = r - 192; soff = (size_t)l * 262144; doff = W_W20 + soff; K_ = 1024; N_ = 256; }
    int ntil = N_ >> 6;
    int kt = ti / ntil, nt = ti % ntil;
    int k0 = kt * 64, n0 = nt * 64;
    int t = threadIdx.x;
#pragma unroll
    for (int rr = 0; rr < 16; ++rr) {
        int kk = rr * 4 + (t >> 6), nn = t & 63;
        tile[kk][nn] = ldx(src, soff + (size_t)(k0 + kk) * N_ + n0 + nn, bfw);
    }
    __syncthreads();
#pragma unroll
    for (int rr = 0; rr < 16; ++rr) {
        int nn = rr * 4 + (t >> 6), kk = t & 63;
        float v = tile[kk][nn];
        size_t o = doff + (size_t)(n0 + nn) * K_ + k0 + kk;
        split1(v, Wh[o], Wl[o]);
    }
}

// One-time: split shared embedding [V][D]; pad rows V..3007 with 0.
__global__ void embsplit_k(const void* __restrict__ emb,
                           __bf16* __restrict__ Wh, __bf16* __restrict__ Wl,
                           const int* __restrict__ flagp) {
    int bfw = *flagp;
    int row = blockIdx.x;           // 0..3007
    int d = threadIdx.x;
    float v = (row < VV) ? ldx(emb, (size_t)row * DD + d, bfw) : 0.f;
    size_t o = W_EMB0 + (size_t)row * DD + d;
    split1(v, Wh[o], Wl[o]);
}

// x = input_embed[seq] + pos_embed ; also writes hi/lo split of x
__global__ void embed_k(const int* __restrict__ seq,
                        const void* __restrict__ emb,
                        const void* __restrict__ pos,
                        float* __restrict__ x,
                        __bf16* __restrict__ xh,
                        __bf16* __restrict__ xl,
                        const int* __restrict__ flagp) {
    int bf = *flagp;
    int row = blockIdx.x;
    int d = threadIdx.x;
    int s = row & (SS - 1);
    int b = row >> 9;
    int tok = seq[b * SS + s];
    float v = ldx(emb, (size_t)tok * DD + d, bf) + ldx(pos, (size_t)s * DD + d, bf);
    size_t idx = (size_t)row * DD + d;
    x[idx] = v;
    split1(v, xh[idx], xl[idx]);
}

// ---------------------------------------------------------------------------
// Split-bf16 MFMA GEMM.  C[M,N] = A[M,K] @ B[K,N] (+bias)(+relu)
//   B: pre-split [N][K] bf16 hi/lo pairs at Wh/Wl + boff.
//   AMODE 1: A is flag-dtype global, split in-kernel; 2: pre-split pair.
//   OUTMODE 0: fp32 C; 1: split pair C/C2; 2: flag-dtype store, col<N guard.
//   nsplit>0: B rows stacked; C per-mat addressed, advanced by mat*cstride.
// Tile BM=64 BN=64 BK=64, 128 thr = 2 waves, wave 32x64 (2x4 frags 16x16x32).
// LDS tiles XOR-swizzled (swzi). XCD-chunked bijective block swizzle with
// m-major ids: each XCD's L2 sees contiguous A row-panels.
// ---------------------------------------------------------------------------
template <int AMODE, int OUTMODE>
__global__ __launch_bounds__(128, 2)
void gemm_mfma_k(const void* __restrict__ A, const void* __restrict__ Al_,
                 const __bf16* __restrict__ Wh, const __bf16* __restrict__ Wl, size_t boff,
                 const char* __restrict__ biasbase, size_t biasoff, int hasbias,
                 void* __restrict__ C, void* __restrict__ C2,
                 int M, int N, int K, int relu,
                 int nsplit, size_t cstride,
                 const int* __restrict__ flagp) {
    int bfw = *flagp;
    const __bf16* Bh_g = Wh + boff;
    const __bf16* Bl_g = Wl + boff;
    int t = threadIdx.x;
    int lane = t & 63;
    int wv = t >> 6;

    // XCD-chunked bijective swizzle (m204), ids m-major.
    int gx = gridDim.x;
    int nwg = gx * gridDim.y;
    int id = blockIdx.y * gx + blockIdx.x;
    int q = nwg >> 3, r = nwg & 7;
    int xcd = id & 7, sub = id >> 3;
    int nid = (xcd < r ? xcd * (q + 1) : r * (q + 1) + (xcd - r) * q) + sub;
    int nB0 = (nid % gx) * 64;       // GLOBAL n for B loads (stacked rows)
    int m0  = (nid / gx) * 64;

    int n0 = nB0;                    // within-mat n for C addressing
    int ldc = N;
    float* Cf = (float*)C;
    __bf16* Ch = (__bf16*)C;
    __bf16* Cl2 = (__bf16*)C2;
    if (nsplit) {
        int mat = n0 / nsplit;
        n0 -= mat * nsplit;
        Cf  += (size_t)mat * cstride;
        Ch  += (size_t)mat * cstride;
        Cl2 += (size_t)mat * cstride;
        ldc = nsplit;
    }

    __shared__ __align__(16) __bf16 Ah[4096];
    __shared__ __align__(16) __bf16 Al[4096];
    __shared__ __align__(16) __bf16 Bh[4096];
    __shared__ __align__(16) __bf16 Bl[4096];

    f32x4 acc[2][4] = {};
    int fr = lane & 15;
    int fg = lane >> 4;
    int t_alo = !(AMODE == 1 && bfw);
    int t_blo = !bfw;

    int srow = t >> 1;               // staging row 0..63
    int sk   = (t & 1) * 32;         // k-base within BK
    int sc0  = (t & 1) * 4;          // chunk base

    bf16x8 pah[4], pal[4], pbh[4], pbl[4];

    auto loadA = [&](int k0) {
#pragma unroll
        for (int j = 0; j < 4; ++j) {
            size_t g = (size_t)(m0 + srow) * K + k0 + sk + j * 8;
            if (AMODE == 2) {
                pah[j] = *(const bf16x8*)((const __bf16*)A + g);
                pal[j] = *(const bf16x8*)((const __bf16*)Al_ + g);
            } else if (bfw) {
                pah[j] = *(const bf16x8*)((const __hip_bfloat16*)A + g);
            } else {
                float4 f1 = *(const float4*)((const float*)A + g);
                float4 f2 = *(const float4*)((const float*)A + g + 4);
                float vv[8] = {f1.x, f1.y, f1.z, f1.w, f2.x, f2.y, f2.z, f2.w};
                bf16x8 hv, lv;
#pragma unroll
                for (int e = 0; e < 8; ++e) { __bf16 h, l; split1(vv[e], h, l); hv[e] = h; lv[e] = l; }
                pah[j] = hv; pal[j] = lv;
            }
        }
    };
    auto loadB = [&](int k0) {
#pragma unroll
        for (int j = 0; j < 4; ++j) {
            size_t g = (size_t)(nB0 + srow) * K + k0 + sk + j * 8;
            pbh[j] = *(const bf16x8*)(Bh_g + g);
            pbl[j] = *(const bf16x8*)(Bl_g + g);
        }
    };
    auto writeLDS = [&]() {
#pragma unroll
        for (int j = 0; j < 4; ++j) {
            int o = swzi(srow, sc0 + j);
            *(bf16x8*)&Ah[o] = pah[j];
            if (!(AMODE == 1 && bfw)) *(bf16x8*)&Al[o] = pal[j];
            *(bf16x8*)&Bh[o] = pbh[j];
            *(bf16x8*)&Bl[o] = pbl[j];
        }
    };

    loadA(0); loadB(0);
    for (int k0 = 0; k0 < K; k0 += 64) {
        writeLDS();
        __syncthreads();
        if (k0 + 64 < K) { loadA(k0 + 64); loadB(k0 + 64); }

#pragma unroll
        for (int ks = 0; ks < 2; ++ks) {
            bf16x8 afh[2], afl[2], bgh[4], bgl[4];
#pragma unroll
            for (int f = 0; f < 2; ++f) {
                int o = swzi(wv * 32 + f * 16 + fr, ks * 4 + fg);
                afh[f] = *(const bf16x8*)&Ah[o];
                afl[f] = *(const bf16x8*)&Al[o];
            }
#pragma unroll
            for (int f = 0; f < 4; ++f) {
                int o = swzi(f * 16 + fr, ks * 4 + fg);
                bgh[f] = *(const bf16x8*)&Bh[o];
                bgl[f] = *(const bf16x8*)&Bl[o];
            }
#pragma unroll
            for (int mf = 0; mf < 2; ++mf)
#pragma unroll
                for (int nf = 0; nf < 4; ++nf) {
                    acc[mf][nf] = __builtin_amdgcn_mfma_f32_16x16x32_bf16(afh[mf], bgh[nf], acc[mf][nf], 0, 0, 0);
                    if (t_alo)
                        acc[mf][nf] = __builtin_amdgcn_mfma_f32_16x16x32_bf16(afl[mf], bgh[nf], acc[mf][nf], 0, 0, 0);
                    if (t_blo)
                        acc[mf][nf] = __builtin_amdgcn_mfma_f32_16x16x32_bf16(afh[mf], bgl[nf], acc[mf][nf], 0, 0, 0);
                }
        }
        __syncthreads();
    }

    const char* biasp = biasbase + biasoff * (bfw ? 2 : 4);
#pragma unroll
    for (int mf = 0; mf < 2; ++mf)
#pragma unroll
        for (int nf = 0; nf < 4; ++nf)
#pragma unroll
            for (int r2 = 0; r2 < 4; ++r2) {
                int row = m0 + wv * 32 + mf * 16 + fg * 4 + r2;
                int col = n0 + nf * 16 + fr;
                float v = acc[mf][nf][r2];
                if (OUTMODE == 2) {
                    if (col < N) {
                        v += ldx(biasp, col, bfw);
                        size_t oi = (size_t)row * N + col;
                        if (bfw) ((__hip_bfloat16*)C)[oi] = __float2bfloat16(v);
                        else     ((float*)C)[oi] = v;
                    }
                } else {
                    if (hasbias) v += ldx(biasp, col, bfw);
                    if (relu) v = fmaxf(v, 0.f);
                    size_t oi = (size_t)row * ldc + col;
                    if (OUTMODE == 1) {
                        __bf16 h, l; split1(v, h, l);
                        Ch[oi]  = h;
                        Cl2[oi] = l;
                    } else {
                        Cf[oi] = v;
                    }
                }
            }
}

// ---------------------------------------------------------------------------
// MFMA flash attention on pre-split bf16 pairs. Block = (b,h,64 q) -> 1024
// blocks, 4 waves; wave owns 16 q-rows. K/V staging = pure pair copies.
// ---------------------------------------------------------------------------
template <int CAUSAL>
__global__ __launch_bounds__(256)
void attn_mfma_k(const __bf16* __restrict__ Qh_g, const __bf16* __restrict__ Ql_g,
                 const __bf16* __restrict__ Kh_g, const __bf16* __restrict__ Kl_g,
                 const __bf16* __restrict__ Vh_g, const __bf16* __restrict__ Vl_g,
                 __bf16* __restrict__ Oh, __bf16* __restrict__ Ol,
                 int Sk) {
    __shared__ __align__(16) __bf16 Kh[64][40];
    __shared__ __align__(16) __bf16 Kl[64][40];
    __shared__ __align__(16) __bf16 Vh[32][72];
    __shared__ __align__(16) __bf16 Vl[32][72];
    __shared__ __align__(16) __bf16 Ph[4][16][72];
    __shared__ __align__(16) __bf16 Pl[4][16][72];

    int t = threadIdx.x;
    int lane = t & 63;
    int w = t >> 6;
    int l15 = lane & 15;
    int g = lane >> 4;

    int blk = blockIdx.x;           // (b*HH + h)*8 + qt
    int qt = blk & 7;
    int h  = (blk >> 3) & (HH - 1);
    int b  = blk >> 6;
    int q0 = qt * 64;

    const float scale = 0.17677669529663689f;  // 1/sqrt(32)

    bf16x8 qh_, ql_;
    {
        size_t qi = ((size_t)(b * SS + q0 + w * 16 + l15)) * DD + h * 32 + g * 8;
        bf16x8 qh8 = *(const bf16x8*)(Qh_g + qi);
        bf16x8 ql8 = *(const bf16x8*)(Ql_g + qi);
#pragma unroll
        for (int j = 0; j < 8; ++j) {
            float v = ((float)qh8[j] + (float)ql8[j]) * scale;
            __bf16 hh, ll; split1(v, hh, ll);
            qh_[j] = hh; ql_[j] = ll;
        }
    }

    f32x4 oacc[2] = {};
    float m_r[4] = {-1e30f, -1e30f, -1e30f, -1e30f};
    float l_r[4] = {0.f, 0.f, 0.f, 0.f};

    int ntiles = CAUSAL ? (qt + 1) : (Sk >> 6);

    for (int tt = 0; tt < ntiles; ++tt) {
        int j0 = tt * 64;
        {
            int row = t >> 2, db = (t & 3) * 8;
            size_t gi = ((size_t)(b * Sk + j0 + row)) * DD + h * 32 + db;
            *(bf16x8*)&Kh[row][db] = *(const bf16x8*)(Kh_g + gi);
            *(bf16x8*)&Kl[row][db] = *(const bf16x8*)(Kl_g + gi);
            bf16x8 vh8 = *(const bf16x8*)(Vh_g + gi);
            bf16x8 vl8 = *(const bf16x8*)(Vl_g + gi);
#pragma unroll
            for (int j = 0; j < 8; ++j) {
                Vh[db + j][row] = vh8[j];
                Vl[db + j][row] = vl8[j];
            }
        }
        __syncthreads();

        f32x4 s[4] = {};
#pragma unroll
        for (int kt = 0; kt < 4; ++kt) {
            bf16x8 kbh = *(const bf16x8*)&Kh[kt * 16 + l15][g * 8];
            bf16x8 kbl = *(const bf16x8*)&Kl[kt * 16 + l15][g * 8];
            s[kt] = __builtin_amdgcn_mfma_f32_16x16x32_bf16(qh_, kbh, s[kt], 0, 0, 0);
            s[kt] = __builtin_amdgcn_mfma_f32_16x16x32_bf16(ql_, kbh, s[kt], 0, 0, 0);
            s[kt] = __builtin_amdgcn_mfma_f32_16x16x32_bf16(qh_, kbl, s[kt], 0, 0, 0);
        }

        if (CAUSAL && tt == ntiles - 1) {
            int qa_ = q0 + w * 16 + g * 4;
#pragma unroll
            for (int kt = 0; kt < 4; ++kt)
#pragma unroll
                for (int r = 0; r < 4; ++r)
                    if (j0 + kt * 16 + l15 > qa_ + r) s[kt][r] = -1e30f;
        }

        float al_r[4];
#pragma unroll
        for (int r = 0; r < 4; ++r) {
            float mx = fmaxf(fmaxf(s[0][r], s[1][r]), fmaxf(s[2][r], s[3][r]));
#pragma unroll
            for (int off = 1; off < 16; off <<= 1) mx = fmaxf(mx, __shfl_xor(mx, off));
            float mnew = fmaxf(m_r[r], mx);
            al_r[r] = __expf(m_r[r] - mnew);
            float ps = 0.f;
#pragma unroll
            for (int kt = 0; kt < 4; ++kt) {
                float p = __expf(s[kt][r] - mnew);
                s[kt][r] = p;
                ps += p;
            }
#pragma unroll
            for (int off = 1; off < 16; off <<= 1) ps += __shfl_xor(ps, off);
            l_r[r] = l_r[r] * al_r[r] + ps;
            m_r[r] = mnew;
        }
#pragma unroll
        for (int dt = 0; dt < 2; ++dt)
#pragma unroll
            for (int r = 0; r < 4; ++r) oacc[dt][r] *= al_r[r];
#pragma unroll
        for (int kt = 0; kt < 4; ++kt)
#pragma unroll
            for (int r = 0; r < 4; ++r) {
                __bf16 hh, ll; split1(s[kt][r], hh, ll);
                Ph[w][g * 4 + r][kt * 16 + l15] = hh;
                Pl[w][g * 4 + r][kt * 16 + l15] = ll;
            }
        __syncthreads();

#pragma unroll
        for (int kc = 0; kc < 2; ++kc) {
            bf16x8 pa  = *(const bf16x8*)&Ph[w][l15][kc * 32 + g * 8];
            bf16x8 pal = *(const bf16x8*)&Pl[w][l15][kc * 32 + g * 8];
#pragma unroll
            for (int dt = 0; dt < 2; ++dt) {
                bf16x8 vb  = *(const bf16x8*)&Vh[dt * 16 + l15][kc * 32 + g * 8];
                bf16x8 vbl = *(const bf16x8*)&Vl[dt * 16 + l15][kc * 32 + g * 8];
                oacc[dt] = __builtin_amdgcn_mfma_f32_16x16x32_bf16(pa, vb, oacc[dt], 0, 0, 0);
                oacc[dt] = __builtin_amdgcn_mfma_f32_16x16x32_bf16(pal, vb, oacc[dt], 0, 0, 0);
                oacc[dt] = __builtin_amdgcn_mfma_f32_16x16x32_bf16(pa, vbl, oacc[dt], 0, 0, 0);
            }
        }
        __syncthreads();
    }

    float inv[4];
#pragma unroll
    for (int r = 0; r < 4; ++r) inv[r] = 1.f / l_r[r];
#pragma unroll
    for (int dt = 0; dt < 2; ++dt)
#pragma unroll
        for (int r = 0; r < 4; ++r) {
            float v = oacc[dt][r] * inv[r];
            size_t oi = ((size_t)(b * SS + q0 + w * 16 + g * 4 + r)) * DD + h * 32 + dt * 16 + l15;
            __bf16 hh, ll; split1(v, hh, ll);
            Oh[oi] = hh;
            Ol[oi] = ll;
        }
}

// x = LN(x + h); also writes hi/lo split of new x.
__global__ void add_ln_k(float* __restrict__ x,
                         const float* __restrict__ hbuf,
                         __bf16* __restrict__ xh,
                         __bf16* __restrict__ xl,
                         const char* __restrict__ gbase, size_t goff,
                         const char* __restrict__ bbase, size_t boff,
                         const int* __restrict__ flagp) {
    int bf = *flagp;
    const void* g = gbase + goff * (bf ? 2 : 4);
    const void* bb = bbase + boff * (bf ? 2 : 4);
    int row = blockIdx.x;
    int d = threadIdx.x;
    float v = x[(size_t)row * DD + d];
    if (hbuf) v += hbuf[(size_t)row * DD + d];
    float s = v, s2 = v * v;
#pragma unroll
    for (int off = 32; off > 0; off >>= 1) {
        s += __shfl_down(s, off);
        s2 += __shfl_down(s2, off);
    }
    __shared__ float sh[8];
    int w = d >> 6;
    if ((d & 63) == 0) { sh[w] = s; sh[4 + w] = s2; }
    __syncthreads();
    if (d == 0) {
        sh[0] = sh[0] + sh[1] + sh[2] + sh[3];
        sh[4] = sh[4] + sh[5] + sh[6] + sh[7];
    }
    __syncthreads();
    float mu = sh[0] * (1.f / DD);
    float var = fmaxf(sh[4] * (1.f / DD) - mu * mu, 0.f);
    float inv = rsqrtf(var + 1e-5f);
    float o = (v - mu) * inv * ldx(g, d, bf) + ldx(bb, d, bf);
    size_t idx = (size_t)row * DD + d;
    x[idx] = o;
    split1(o, xh[idx], xl[idx]);
}

extern "C" void kernel_launch(void* const* d_in, const int* in_sizes, int n_in,
                              void* d_out, int out_size, void* d_ws, size_t ws_size,
                              hipStream_t stream) {
    const void* encoded     = d_in[0];
    const int*  seq         = (const int*)d_in[1];
    const void* input_embed = d_in[2];
    const void* pos_embed   = d_in[3];
    const void* output_bias = d_in[4];
    const void* sa_qkv      = d_in[5];
    const void* sa_o        = d_in[6];
    const void* ca_q        = d_in[7];
    const void* ca_kv       = d_in[8];
    const void* ca_o        = d_in[9];
    const void* ffn_w1      = d_in[10];
    const char* ffn_b1      = (const char*)d_in[11];
    const void* ffn_w2      = d_in[12];
    const char* ffn_b2      = (const char*)d_in[13];
    const char* ln_g        = (const char*)d_in[14];
    const char* ln_b        = (const char*)d_in[15];
    const char* fin_g       = (const char*)d_in[16];
    const char* fin_b       = (const char*)d_in[17];

    const size_t NTOK = (size_t)BB * SS;          // 8192
    const size_t NENC = (size_t)BB * MM;          // 16384

    // Workspace layout (~99 MiB)
    char* p = (char*)d_ws;
    int*    flag = (int*)p;            p += 256;
    float*  x    = (float*)p;          p += NTOK * DD * 4;       // 8 MiB
    __bf16* xh   = (__bf16*)p;         p += NTOK * DD * 2;       // 4 MiB
    __bf16* xl   = (__bf16*)p;         p += NTOK * DD * 2;       // 4 MiB
    __bf16* SAh  = (__bf16*)p;         p += 3 * NTOK * DD * 2;   // 12 MiB (Q,K,V self)
    __bf16* SAl  = (__bf16*)p;         p += 3 * NTOK * DD * 2;   // 12 MiB
    __bf16* CKh  = (__bf16*)p;         p += 2 * NENC * DD * 2;   // 16 MiB (cross K,V / FFN H)
    __bf16* CKl  = (__bf16*)p;         p += 2 * NENC * DD * 2;   // 16 MiB
    __bf16* Wh   = (__bf16*)p;         p += (size_t)W_TOT * 2;   // 13.5 MiB
    __bf16* Wl   = (__bf16*)p;         p += (size_t)W_TOT * 2;   // 13.5 MiB
    // aliases (lifetimes verified):
    float*  Tb = (float*)(SAh + NTOK * DD);   // 8 MiB in dead self-K/V hi space
    __bf16* Qh = SAh;  __bf16* Ql = SAl;      // self Q and cross Q
    __bf16* Oh = xh;   __bf16* Ol = xl;       // attn O (xh/xl dead in between)
    __bf16* Hh = CKh;  __bf16* Hl = CKl;      // FFN hidden pairs

    detect_k<<<1, 256, 0, stream>>>((const unsigned int*)input_embed, flag);
    wsplit_k<<<1536, 256, 0, stream>>>(sa_qkv, sa_o, ca_q, ca_kv, ca_o,
                                       ffn_w1, ffn_w2, Wh, Wl, flag);
    embsplit_k<<<3008, 256, 0, stream>>>(input_embed, Wh, Wl, flag);
    embed_k<<<NTOK, 256, 0, stream>>>(seq, input_embed, pos_embed, x, xh, xl, flag);

    dim3 blk(128);
    dim3 gQKV(12, 128);                // N=768 (3 mats), M=8192
    dim3 gP(4, 128);                   // N=256, M=8192
    dim3 gCKV(8, 256);                 // N=512 (2 mats), M=16384
    dim3 gW1(16, 128);                 // N=1024, M=8192
    dim3 gOut(47, 128);                // N=3000 (guarded), M=8192
    int attn_blocks = BB * HH * (SS / 64);   // 1024

    for (int l = 0; l < LL; ++l) {
        size_t oQKV = W_QKV0 + (size_t)l * 3 * 65536;
        size_t oSAO = W_SAO0 + (size_t)l * 65536;
        size_t oCAQ = W_CAQ0 + (size_t)l * 65536;
        size_t oCKV = W_CKV0 + (size_t)l * 2 * 65536;
        size_t oCAO = W_CAO0 + (size_t)l * 65536;
        size_t oW1  = W_W10  + (size_t)l * 262144;
        size_t oW2  = W_W20  + (size_t)l * 262144;
        size_t oB1  = (size_t)l * FF;
        size_t oB2  = (size_t)l * DD;
        size_t oG   = (size_t)l * 3 * DD;

        // --- self attention ---
        gemm_mfma_k<2, 1><<<gQKV, blk, 0, stream>>>(xh, xl, Wh, Wl, oQKV,
            nullptr, 0, 0, SAh, SAl, (int)NTOK, 3 * DD, DD, 0, DD, NTOK * DD, flag);
        attn_mfma_k<1><<<attn_blocks, 256, 0, stream>>>(Qh, Ql,
            SAh + NTOK * DD, SAl + NTOK * DD, SAh + 2 * NTOK * DD, SAl + 2 * NTOK * DD,
            Oh, Ol, SS);
        gemm_mfma_k<2, 0><<<gP, blk, 0, stream>>>(Oh, Ol, Wh, Wl, oSAO,
            nullptr, 0, 0, Tb, nullptr, (int)NTOK, DD, DD, 0, 0, 0, flag);
        add_ln_k<<<NTOK, 256, 0, stream>>>(x, Tb, xh, xl, ln_g, oG, ln_b, oG, flag);
        // --- cross attention ---
        gemm_mfma_k<2, 1><<<gP, blk, 0, stream>>>(xh, xl, Wh, Wl, oCAQ,
            nullptr, 0, 0, Qh, Ql, (int)NTOK, DD, DD, 0, 0, 0, flag);
        gemm_mfma_k<1, 1><<<gCKV, blk, 0, stream>>>(encoded, nullptr, Wh, Wl, oCKV,
            nullptr, 0, 0, CKh, CKl, (int)NENC, 2 * DD, DD, 0, DD, NENC * DD, flag);
        attn_mfma_k<0><<<attn_blocks, 256, 0, stream>>>(Qh, Ql,
            CKh, CKl, CKh + NENC * DD, CKl + NENC * DD, Oh, Ol, MM);
        gemm_mfma_k<2, 0><<<gP, blk, 0, stream>>>(Oh, Ol, Wh, Wl, oCAO,
            nullptr, 0, 0, Tb, nullptr, (int)NTOK, DD, DD, 0, 0, 0, flag);
        add_ln_k<<<NTOK, 256, 0, stream>>>(x, Tb, xh, xl, ln_g, oG + DD, ln_b, oG + DD, flag);
        // --- FFN ---
        gemm_mfma_k<2, 1><<<gW1, blk, 0, stream>>>(xh, xl, Wh, Wl, oW1,
            ffn_b1, oB1, 1, Hh, Hl, (int)NTOK, FF, DD, 1, 0, 0, flag);
        gemm_mfma_k<2, 0><<<gP, blk, 0, stream>>>(Hh, Hl, Wh, Wl, oW2,
            ffn_b2, oB2, 1, Tb, nullptr, (int)NTOK, DD, FF, 0, 0, 0, flag);
        add_ln_k<<<NTOK, 256, 0, stream>>>(x, Tb, xh, xl, ln_g, oG + 2 * DD, ln_b, oG + 2 * DD, flag);
    }
    // final norm + shared-embedding logits
    add_ln_k<<<NTOK, 256, 0, stream>>>(x, nullptr, xh, xl, fin_g, 0, fin_b, 0, flag);
    gemm_mfma_k<2, 2><<<gOut, blk, 0, stream>>>(xh, xl, Wh, Wl, W_EMB0,
        (const char*)output_bias, 0, 1, d_out, nullptr, (int)NTOK, VV, DD, 0, 0, 0, flag);
}

// Round 6
// 2157.808 us; speedup vs baseline: 1.0825x; 1.0825x over previous
//
#include <hip/hip_runtime.h>
#include <hip/hip_bf16.h>

#define DD 256
#define HH 8
#define DH 32
#define SS 512
#define MM 1024
#define BB 16
#define FF 1024
#define LL 6
#define VV 3000

typedef __bf16 bf16x8 __attribute__((ext_vector_type(8)));
typedef float  f32x4  __attribute__((ext_vector_type(4)));

// Wt layout offsets (elements). All matrices stored [N][K] bf16 hi/lo pairs.
#define W_QKV0 0u
#define W_SAO0 1179648u
#define W_CAQ0 1572864u
#define W_CKV0 1966080u
#define W_CAO0 2752512u
#define W_W10  3145728u
#define W_W20  4718592u
#define W_EMB0 6291456u
#define W_TOT  7061504u   // 6291456 + 3008*256

// Mixed-dtype load: bf==1 -> bf16, bf==0 -> fp32.
__device__ __forceinline__ float ldx(const void* p, size_t i, int bf) {
    if (bf) return __bfloat162float(((const __hip_bfloat16*)p)[i]);
    return ((const float*)p)[i];
}

// fp32 -> bf16 hi/lo split: v = hi + lo + O(2^-17 * v)
__device__ __forceinline__ void split1(float v, __bf16& h, __bf16& l) {
    h = (__bf16)v;
    l = (__bf16)(v - (float)h);
}

// LDS index with XOR chunk swizzle on a [64 rows][64 el] bf16 tile (128-B
// rows, 8 chunks of 16B). chunk c at row r lives at c ^ (r&7).
// Fragment reads: 16 lanes spread over 8 bank-quads = 2/quad (free, m136).
// Staging writes: 64 lanes spread 8/quad = structural floor.
__device__ __forceinline__ int swzi(int row, int c) {
    return row * 64 + ((c ^ (row & 7)) << 3);
}

// dtype detector: writes 1 if buffer is bf16, 0 if fp32.
__global__ void detect_k(const unsigned int* __restrict__ w, int* __restrict__ flag) {
    int t = threadIdx.x;
    unsigned int v = w[t];
    int ok = 1;
#pragma unroll
    for (int h = 0; h < 2; ++h) {
        unsigned int hw = (v >> (16 * h)) & 0xFFFFu;
        unsigned int e = (hw >> 7) & 0xFFu;
        if (!((e >= 90u && e <= 140u) || (hw & 0x7FFFu) == 0u)) ok = 0;
    }
    __shared__ int allok;
    if (t == 0) allok = 1;
    __syncthreads();
    if (!ok) atomicAnd(&allok, 0);
    __syncthreads();
    if (t == 0) *flag = allok;
}

// One-time: transpose+split all layer weights into [N][K] bf16 hi/lo pairs.
__global__ __launch_bounds__(256)
void wsplit_k(const void* __restrict__ sa_qkv, const void* __restrict__ sa_o,
              const void* __restrict__ ca_q, const void* __restrict__ ca_kv,
              const void* __restrict__ ca_o, const void* __restrict__ w1,
              const void* __restrict__ w2,
              __bf16* __restrict__ Wh, __bf16* __restrict__ Wl,
              const int* __restrict__ flagp) {
    int bfw = *flagp;
    __shared__ float tile[64][65];
    int blk = blockIdx.x;
    int l = blk >> 8, r = blk & 255;
    const void* src; size_t soff, doff; int K_, N_, ti;
    if (r < 48)       { src = sa_qkv; int j = r >> 4; ti = r & 15;
                        soff = (size_t)(l * 3 + j) * 65536; doff = W_QKV0 + soff; K_ = 256; N_ = 256; }
    else if (r < 64)  { src = sa_o;  ti = r - 48;  soff = (size_t)l * 65536; doff = W_SAO0 + soff; K_ = 256; N_ = 256; }
    else if (r < 80)  { src = ca_q;  ti = r - 64;  soff = (size_t)l * 65536; doff = W_CAQ0 + soff; K_ = 256; N_ = 256; }
    else if (r < 112) { src = ca_kv; int j = (r - 80) >> 4; ti = (r - 80) & 15;
                        soff = (size_t)(l * 2 + j) * 65536; doff = W_CKV0 + soff; K_ = 256; N_ = 256; }
    else if (r < 128) { src = ca_o;  ti = r - 112; soff = (size_t)l * 65536; doff = W_CAO0 + soff; K_ = 256; N_ = 256; }
    else if (r < 192) { src = w1;    ti = r - 128; soff = (size_t)l * 262144; doff = W_W10 + soff; K_ = 256; N_ = 1024; }
    else              { src = w2;    ti = r - 192; soff = (size_t)l * 262144; doff = W_W20 + soff; K_ = 1024; N_ = 256; }
    int ntil = N_ >> 6;
    int kt = ti / ntil, nt = ti % ntil;
    int k0 = kt * 64, n0 = nt * 64;
    int t = threadIdx.x;
#pragma unroll
    for (int rr = 0; rr < 16; ++rr) {
        int kk = rr * 4 + (t >> 6), nn = t & 63;
        tile[kk][nn] = ldx(src, soff + (size_t)(k0 + kk) * N_ + n0 + nn, bfw);
    }
    __syncthreads();
#pragma unroll
    for (int rr = 0; rr < 16; ++rr) {
        int nn = rr * 4 + (t >> 6), kk = t & 63;
        float v = tile[kk][nn];
        size_t o = doff + (size_t)(n0 + nn) * K_ + k0 + kk;
        split1(v, Wh[o], Wl[o]);
    }
}

// One-time: split shared embedding [V][D]; pad rows V..3007 with 0.
__global__ void embsplit_k(const void* __restrict__ emb,
                           __bf16* __restrict__ Wh, __bf16* __restrict__ Wl,
                           const int* __restrict__ flagp) {
    int bfw = *flagp;
    int row = blockIdx.x;           // 0..3007
    int d = threadIdx.x;
    float v = (row < VV) ? ldx(emb, (size_t)row * DD + d, bfw) : 0.f;
    size_t o = W_EMB0 + (size_t)row * DD + d;
    split1(v, Wh[o], Wl[o]);
}

// x = input_embed[seq] + pos_embed ; also writes hi/lo split of x
__global__ void embed_k(const int* __restrict__ seq,
                        const void* __restrict__ emb,
                        const void* __restrict__ pos,
                        float* __restrict__ x,
                        __bf16* __restrict__ xh,
                        __bf16* __restrict__ xl,
                        const int* __restrict__ flagp) {
    int bf = *flagp;
    int row = blockIdx.x;
    int d = threadIdx.x;
    int s = row & (SS - 1);
    int b = row >> 9;
    int tok = seq[b * SS + s];
    float v = ldx(emb, (size_t)tok * DD + d, bf) + ldx(pos, (size_t)s * DD + d, bf);
    size_t idx = (size_t)row * DD + d;
    x[idx] = v;
    split1(v, xh[idx], xl[idx]);
}

// ---------------------------------------------------------------------------
// Split-bf16 MFMA GEMM.  C[M,N] = A[M,K] @ B[K,N] (+bias)(+relu)
//   B: pre-split [N][K] bf16 hi/lo pairs at Wh/Wl + boff.
//   AMODE 1: A is flag-dtype global, split in-kernel; 2: pre-split pair.
//   OUTMODE 0: fp32 C; 1: split pair C/C2; 2: flag-dtype store, col<N guard.
//   nsplit>0: B rows stacked; C per-mat addressed, advanced by mat*cstride.
// Tile BM=64 BN=64 BK=32, 128 thr = 2 waves, wave 32x64 (2x4 frags 16x16x32).
// LDS: PACKED hi/lo tiles Ahl/Bhl [64][64] (cols 0..31 hi, 32..63 lo) with
// swzi XOR swizzle -> 16 KB total, conflict-free reads AND writes.
// XCD-chunked bijective block swizzle (m204) for L2 locality.
// ---------------------------------------------------------------------------
template <int AMODE, int OUTMODE>
__global__ __launch_bounds__(128, 3)
void gemm_mfma_k(const void* __restrict__ A, const void* __restrict__ Al_,
                 const __bf16* __restrict__ Wh, const __bf16* __restrict__ Wl, size_t boff,
                 const char* __restrict__ biasbase, size_t biasoff, int hasbias,
                 void* __restrict__ C, void* __restrict__ C2,
                 int M, int N, int K, int relu,
                 int nsplit, size_t cstride,
                 const int* __restrict__ flagp) {
    int bfw = *flagp;
    const __bf16* Bh_g = Wh + boff;
    const __bf16* Bl_g = Wl + boff;
    int t = threadIdx.x;
    int lane = t & 63;
    int wv = t >> 6;

    // XCD-chunked bijective swizzle (m204), ids m-major.
    int gx = gridDim.x;
    int nwg = gx * gridDim.y;
    int id = blockIdx.y * gx + blockIdx.x;
    int q = nwg >> 3, r = nwg & 7;
    int xcd = id & 7, sub = id >> 3;
    int nid = (xcd < r ? xcd * (q + 1) : r * (q + 1) + (xcd - r) * q) + sub;
    int nB0 = (nid % gx) * 64;       // GLOBAL n for B loads (stacked rows)
    int m0  = (nid / gx) * 64;

    int n0 = nB0;                    // within-mat n for C addressing
    int ldc = N;
    float* Cf = (float*)C;
    __bf16* Ch = (__bf16*)C;
    __bf16* Cl2 = (__bf16*)C2;
    if (nsplit) {
        int mat = n0 / nsplit;
        n0 -= mat * nsplit;
        Cf  += (size_t)mat * cstride;
        Ch  += (size_t)mat * cstride;
        Cl2 += (size_t)mat * cstride;
        ldc = nsplit;
    }

    __shared__ __align__(16) __bf16 Ahl[4096];   // [64][64] packed hi|lo
    __shared__ __align__(16) __bf16 Bhl[4096];

    f32x4 acc[2][4] = {};
    int fr = lane & 15;
    int fg = lane >> 4;
    int t_alo = !(AMODE == 1 && bfw);
    int t_blo = !bfw;

    int srow = t >> 1;               // staging row 0..63
    int h2 = t & 1;                  // k-half: elements h2*16 .. h2*16+15

    bf16x8 pah[2], pal[2], pbh[2], pbl[2];

    auto loadA = [&](int k0) {
        size_t g = (size_t)(m0 + srow) * K + k0 + h2 * 16;
        if (AMODE == 2) {
            pah[0] = *(const bf16x8*)((const __bf16*)A + g);
            pah[1] = *(const bf16x8*)((const __bf16*)A + g + 8);
            pal[0] = *(const bf16x8*)((const __bf16*)Al_ + g);
            pal[1] = *(const bf16x8*)((const __bf16*)Al_ + g + 8);
        } else if (bfw) {
            pah[0] = *(const bf16x8*)((const __hip_bfloat16*)A + g);
            pah[1] = *(const bf16x8*)((const __hip_bfloat16*)A + g + 8);
        } else {
#pragma unroll
            for (int c = 0; c < 2; ++c) {
                float4 f1 = *(const float4*)((const float*)A + g + c * 8);
                float4 f2 = *(const float4*)((const float*)A + g + c * 8 + 4);
                float vv[8] = {f1.x, f1.y, f1.z, f1.w, f2.x, f2.y, f2.z, f2.w};
                bf16x8 hv, lv;
#pragma unroll
                for (int e = 0; e < 8; ++e) { __bf16 h, l; split1(vv[e], h, l); hv[e] = h; lv[e] = l; }
                pah[c] = hv; pal[c] = lv;
            }
        }
    };
    auto loadB = [&](int k0) {
        size_t g = (size_t)(nB0 + srow) * K + k0 + h2 * 16;
        pbh[0] = *(const bf16x8*)(Bh_g + g);
        pbh[1] = *(const bf16x8*)(Bh_g + g + 8);
        pbl[0] = *(const bf16x8*)(Bl_g + g);
        pbl[1] = *(const bf16x8*)(Bl_g + g + 8);
    };
    auto writeLDS = [&]() {
#pragma unroll
        for (int j = 0; j < 2; ++j) {
            int ch = h2 * 2 + j;                       // hi chunk 0..3
            *(bf16x8*)&Ahl[swzi(srow, ch)] = pah[j];
            *(bf16x8*)&Bhl[swzi(srow, ch)] = pbh[j];
            *(bf16x8*)&Bhl[swzi(srow, 4 + ch)] = pbl[j];
            if (!(AMODE == 1 && bfw))
                *(bf16x8*)&Ahl[swzi(srow, 4 + ch)] = pal[j];
        }
    };

    loadA(0); loadB(0);
    for (int k0 = 0; k0 < K; k0 += 32) {
        writeLDS();
        __syncthreads();
        if (k0 + 32 < K) { loadA(k0 + 32); loadB(k0 + 32); }

        bf16x8 afh[2], afl[2], bgh[4], bgl[4];
#pragma unroll
        for (int f = 0; f < 2; ++f) {
            int row = wv * 32 + f * 16 + fr;
            afh[f] = *(const bf16x8*)&Ahl[swzi(row, fg)];
            afl[f] = *(const bf16x8*)&Ahl[swzi(row, 4 + fg)];
        }
#pragma unroll
        for (int f = 0; f < 4; ++f) {
            int row = f * 16 + fr;
            bgh[f] = *(const bf16x8*)&Bhl[swzi(row, fg)];
            bgl[f] = *(const bf16x8*)&Bhl[swzi(row, 4 + fg)];
        }
#pragma unroll
        for (int mf = 0; mf < 2; ++mf)
#pragma unroll
            for (int nf = 0; nf < 4; ++nf) {
                acc[mf][nf] = __builtin_amdgcn_mfma_f32_16x16x32_bf16(afh[mf], bgh[nf], acc[mf][nf], 0, 0, 0);
                if (t_alo)
                    acc[mf][nf] = __builtin_amdgcn_mfma_f32_16x16x32_bf16(afl[mf], bgh[nf], acc[mf][nf], 0, 0, 0);
                if (t_blo)
                    acc[mf][nf] = __builtin_amdgcn_mfma_f32_16x16x32_bf16(afh[mf], bgl[nf], acc[mf][nf], 0, 0, 0);
            }
        __syncthreads();
    }

    const char* biasp = biasbase + biasoff * (bfw ? 2 : 4);
#pragma unroll
    for (int mf = 0; mf < 2; ++mf)
#pragma unroll
        for (int nf = 0; nf < 4; ++nf)
#pragma unroll
            for (int r2 = 0; r2 < 4; ++r2) {
                int row = m0 + wv * 32 + mf * 16 + fg * 4 + r2;
                int col = n0 + nf * 16 + fr;
                float v = acc[mf][nf][r2];
                if (OUTMODE == 2) {
                    if (col < N) {
                        v += ldx(biasp, col, bfw);
                        size_t oi = (size_t)row * N + col;
                        if (bfw) ((__hip_bfloat16*)C)[oi] = __float2bfloat16(v);
                        else     ((float*)C)[oi] = v;
                    }
                } else {
                    if (hasbias) v += ldx(biasp, col, bfw);
                    if (relu) v = fmaxf(v, 0.f);
                    size_t oi = (size_t)row * ldc + col;
                    if (OUTMODE == 1) {
                        __bf16 h, l; split1(v, h, l);
                        Ch[oi]  = h;
                        Cl2[oi] = l;
                    } else {
                        Cf[oi] = v;
                    }
                }
            }
}

// ---------------------------------------------------------------------------
// MFMA flash attention on pre-split bf16 pairs. Block = (b,h,64 q) -> 1024
// blocks, 4 waves; wave owns 16 q-rows. K/V staging = pure pair copies.
// ---------------------------------------------------------------------------
template <int CAUSAL>
__global__ __launch_bounds__(256)
void attn_mfma_k(const __bf16* __restrict__ Qh_g, const __bf16* __restrict__ Ql_g,
                 const __bf16* __restrict__ Kh_g, const __bf16* __restrict__ Kl_g,
                 const __bf16* __restrict__ Vh_g, const __bf16* __restrict__ Vl_g,
                 __bf16* __restrict__ Oh, __bf16* __restrict__ Ol,
                 int Sk) {
    __shared__ __align__(16) __bf16 Kh[64][40];
    __shared__ __align__(16) __bf16 Kl[64][40];
    __shared__ __align__(16) __bf16 Vh[32][72];
    __shared__ __align__(16) __bf16 Vl[32][72];
    __shared__ __align__(16) __bf16 Ph[4][16][72];
    __shared__ __align__(16) __bf16 Pl[4][16][72];

    int t = threadIdx.x;
    int lane = t & 63;
    int w = t >> 6;
    int l15 = lane & 15;
    int g = lane >> 4;

    int blk = blockIdx.x;           // (b*HH + h)*8 + qt
    int qt = blk & 7;
    int h  = (blk >> 3) & (HH - 1);
    int b  = blk >> 6;
    int q0 = qt * 64;

    const float scale = 0.17677669529663689f;  // 1/sqrt(32)

    bf16x8 qh_, ql_;
    {
        size_t qi = ((size_t)(b * SS + q0 + w * 16 + l15)) * DD + h * 32 + g * 8;
        bf16x8 qh8 = *(const bf16x8*)(Qh_g + qi);
        bf16x8 ql8 = *(const bf16x8*)(Ql_g + qi);
#pragma unroll
        for (int j = 0; j < 8; ++j) {
            float v = ((float)qh8[j] + (float)ql8[j]) * scale;
            __bf16 hh, ll; split1(v, hh, ll);
            qh_[j] = hh; ql_[j] = ll;
        }
    }

    f32x4 oacc[2] = {};
    float m_r[4] = {-1e30f, -1e30f, -1e30f, -1e30f};
    float l_r[4] = {0.f, 0.f, 0.f, 0.f};

    int ntiles = CAUSAL ? (qt + 1) : (Sk >> 6);

    for (int tt = 0; tt < ntiles; ++tt) {
        int j0 = tt * 64;
        {
            int row = t >> 2, db = (t & 3) * 8;
            size_t gi = ((size_t)(b * Sk + j0 + row)) * DD + h * 32 + db;
            *(bf16x8*)&Kh[row][db] = *(const bf16x8*)(Kh_g + gi);
            *(bf16x8*)&Kl[row][db] = *(const bf16x8*)(Kl_g + gi);
            bf16x8 vh8 = *(const bf16x8*)(Vh_g + gi);
            bf16x8 vl8 = *(const bf16x8*)(Vl_g + gi);
#pragma unroll
            for (int j = 0; j < 8; ++j) {
                Vh[db + j][row] = vh8[j];
                Vl[db + j][row] = vl8[j];
            }
        }
        __syncthreads();

        f32x4 s[4] = {};
#pragma unroll
        for (int kt = 0; kt < 4; ++kt) {
            bf16x8 kbh = *(const bf16x8*)&Kh[kt * 16 + l15][g * 8];
            bf16x8 kbl = *(const bf16x8*)&Kl[kt * 16 + l15][g * 8];
            s[kt] = __builtin_amdgcn_mfma_f32_16x16x32_bf16(qh_, kbh, s[kt], 0, 0, 0);
            s[kt] = __builtin_amdgcn_mfma_f32_16x16x32_bf16(ql_, kbh, s[kt], 0, 0, 0);
            s[kt] = __builtin_amdgcn_mfma_f32_16x16x32_bf16(qh_, kbl, s[kt], 0, 0, 0);
        }

        if (CAUSAL && tt == ntiles - 1) {
            int qa_ = q0 + w * 16 + g * 4;
#pragma unroll
            for (int kt = 0; kt < 4; ++kt)
#pragma unroll
                for (int r = 0; r < 4; ++r)
                    if (j0 + kt * 16 + l15 > qa_ + r) s[kt][r] = -1e30f;
        }

        float al_r[4];
#pragma unroll
        for (int r = 0; r < 4; ++r) {
            float mx = fmaxf(fmaxf(s[0][r], s[1][r]), fmaxf(s[2][r], s[3][r]));
#pragma unroll
            for (int off = 1; off < 16; off <<= 1) mx = fmaxf(mx, __shfl_xor(mx, off));
            float mnew = fmaxf(m_r[r], mx);
            al_r[r] = __expf(m_r[r] - mnew);
            float ps = 0.f;
#pragma unroll
            for (int kt = 0; kt < 4; ++kt) {
                float p = __expf(s[kt][r] - mnew);
                s[kt][r] = p;
                ps += p;
            }
#pragma unroll
            for (int off = 1; off < 16; off <<= 1) ps += __shfl_xor(ps, off);
            l_r[r] = l_r[r] * al_r[r] + ps;
            m_r[r] = mnew;
        }
#pragma unroll
        for (int dt = 0; dt < 2; ++dt)
#pragma unroll
            for (int r = 0; r < 4; ++r) oacc[dt][r] *= al_r[r];
#pragma unroll
        for (int kt = 0; kt < 4; ++kt)
#pragma unroll
            for (int r = 0; r < 4; ++r) {
                __bf16 hh, ll; split1(s[kt][r], hh, ll);
                Ph[w][g * 4 + r][kt * 16 + l15] = hh;
                Pl[w][g * 4 + r][kt * 16 + l15] = ll;
            }
        __syncthreads();

#pragma unroll
        for (int kc = 0; kc < 2; ++kc) {
            bf16x8 pa  = *(const bf16x8*)&Ph[w][l15][kc * 32 + g * 8];
            bf16x8 pal = *(const bf16x8*)&Pl[w][l15][kc * 32 + g * 8];
#pragma unroll
            for (int dt = 0; dt < 2; ++dt) {
                bf16x8 vb  = *(const bf16x8*)&Vh[dt * 16 + l15][kc * 32 + g * 8];
                bf16x8 vbl = *(const bf16x8*)&Vl[dt * 16 + l15][kc * 32 + g * 8];
                oacc[dt] = __builtin_amdgcn_mfma_f32_16x16x32_bf16(pa, vb, oacc[dt], 0, 0, 0);
                oacc[dt] = __builtin_amdgcn_mfma_f32_16x16x32_bf16(pal, vb, oacc[dt], 0, 0, 0);
                oacc[dt] = __builtin_amdgcn_mfma_f32_16x16x32_bf16(pa, vbl, oacc[dt], 0, 0, 0);
            }
        }
        __syncthreads();
    }

    float inv[4];
#pragma unroll
    for (int r = 0; r < 4; ++r) inv[r] = 1.f / l_r[r];
#pragma unroll
    for (int dt = 0; dt < 2; ++dt)
#pragma unroll
        for (int r = 0; r < 4; ++r) {
            float v = oacc[dt][r] * inv[r];
            size_t oi = ((size_t)(b * SS + q0 + w * 16 + g * 4 + r)) * DD + h * 32 + dt * 16 + l15;
            __bf16 hh, ll; split1(v, hh, ll);
            Oh[oi] = hh;
            Ol[oi] = ll;
        }
}

// x = LN(x + h); also writes hi/lo split of new x.
__global__ void add_ln_k(float* __restrict__ x,
                         const float* __restrict__ hbuf,
                         __bf16* __restrict__ xh,
                         __bf16* __restrict__ xl,
                         const char* __restrict__ gbase, size_t goff,
                         const char* __restrict__ bbase, size_t boff,
                         const int* __restrict__ flagp) {
    int bf = *flagp;
    const void* g = gbase + goff * (bf ? 2 : 4);
    const void* bb = bbase + boff * (bf ? 2 : 4);
    int row = blockIdx.x;
    int d = threadIdx.x;
    float v = x[(size_t)row * DD + d];
    if (hbuf) v += hbuf[(size_t)row * DD + d];
    float s = v, s2 = v * v;
#pragma unroll
    for (int off = 32; off > 0; off >>= 1) {
        s += __shfl_down(s, off);
        s2 += __shfl_down(s2, off);
    }
    __shared__ float sh[8];
    int w = d >> 6;
    if ((d & 63) == 0) { sh[w] = s; sh[4 + w] = s2; }
    __syncthreads();
    if (d == 0) {
        sh[0] = sh[0] + sh[1] + sh[2] + sh[3];
        sh[4] = sh[4] + sh[5] + sh[6] + sh[7];
    }
    __syncthreads();
    float mu = sh[0] * (1.f / DD);
    float var = fmaxf(sh[4] * (1.f / DD) - mu * mu, 0.f);
    float inv = rsqrtf(var + 1e-5f);
    float o = (v - mu) * inv * ldx(g, d, bf) + ldx(bb, d, bf);
    size_t idx = (size_t)row * DD + d;
    x[idx] = o;
    split1(o, xh[idx], xl[idx]);
}

extern "C" void kernel_launch(void* const* d_in, const int* in_sizes, int n_in,
                              void* d_out, int out_size, void* d_ws, size_t ws_size,
                              hipStream_t stream) {
    const void* encoded     = d_in[0];
    const int*  seq         = (const int*)d_in[1];
    const void* input_embed = d_in[2];
    const void* pos_embed   = d_in[3];
    const void* output_bias = d_in[4];
    const void* sa_qkv      = d_in[5];
    const void* sa_o        = d_in[6];
    const void* ca_q        = d_in[7];
    const void* ca_kv       = d_in[8];
    const void* ca_o        = d_in[9];
    const void* ffn_w1      = d_in[10];
    const char* ffn_b1      = (const char*)d_in[11];
    const void* ffn_w2      = d_in[12];
    const char* ffn_b2      = (const char*)d_in[13];
    const char* ln_g        = (const char*)d_in[14];
    const char* ln_b        = (const char*)d_in[15];
    const char* fin_g       = (const char*)d_in[16];
    const char* fin_b       = (const char*)d_in[17];

    const size_t NTOK = (size_t)BB * SS;          // 8192
    const size_t NENC = (size_t)BB * MM;          // 16384

    // Workspace layout (~99 MiB)
    char* p = (char*)d_ws;
    int*    flag = (int*)p;            p += 256;
    float*  x    = (float*)p;          p += NTOK * DD * 4;       // 8 MiB
    __bf16* xh   = (__bf16*)p;         p += NTOK * DD * 2;       // 4 MiB
    __bf16* xl   = (__bf16*)p;         p += NTOK * DD * 2;       // 4 MiB
    __bf16* SAh  = (__bf16*)p;         p += 3 * NTOK * DD * 2;   // 12 MiB (Q,K,V self)
    __bf16* SAl  = (__bf16*)p;         p += 3 * NTOK * DD * 2;   // 12 MiB
    __bf16* CKh  = (__bf16*)p;         p += 2 * NENC * DD * 2;   // 16 MiB (cross K,V / FFN H)
    __bf16* CKl  = (__bf16*)p;         p += 2 * NENC * DD * 2;   // 16 MiB
    __bf16* Wh   = (__bf16*)p;         p += (size_t)W_TOT * 2;   // 13.5 MiB
    __bf16* Wl   = (__bf16*)p;         p += (size_t)W_TOT * 2;   // 13.5 MiB
    // aliases (lifetimes verified):
    float*  Tb = (float*)(SAh + NTOK * DD);   // 8 MiB in dead self-K/V hi space
    __bf16* Qh = SAh;  __bf16* Ql = SAl;      // self Q and cross Q
    __bf16* Oh = xh;   __bf16* Ol = xl;       // attn O (xh/xl dead in between)
    __bf16* Hh = CKh;  __bf16* Hl = CKl;      // FFN hidden pairs

    detect_k<<<1, 256, 0, stream>>>((const unsigned int*)input_embed, flag);
    wsplit_k<<<1536, 256, 0, stream>>>(sa_qkv, sa_o, ca_q, ca_kv, ca_o,
                                       ffn_w1, ffn_w2, Wh, Wl, flag);
    embsplit_k<<<3008, 256, 0, stream>>>(input_embed, Wh, Wl, flag);
    embed_k<<<NTOK, 256, 0, stream>>>(seq, input_embed, pos_embed, x, xh, xl, flag);

    dim3 blk(128);
    dim3 gQKV(12, 128);                // N=768 (3 mats), M=8192
    dim3 gP(4, 128);                   // N=256, M=8192
    dim3 gCKV(8, 256);                 // N=512 (2 mats), M=16384
    dim3 gW1(16, 128);                 // N=1024, M=8192
    dim3 gOut(47, 128);                // N=3000 (guarded), M=8192
    int attn_blocks = BB * HH * (SS / 64);   // 1024

    for (int l = 0; l < LL; ++l) {
        size_t oQKV = W_QKV0 + (size_t)l * 3 * 65536;
        size_t oSAO = W_SAO0 + (size_t)l * 65536;
        size_t oCAQ = W_CAQ0 + (size_t)l * 65536;
        size_t oCKV = W_CKV0 + (size_t)l * 2 * 65536;
        size_t oCAO = W_CAO0 + (size_t)l * 65536;
        size_t oW1  = W_W10  + (size_t)l * 262144;
        size_t oW2  = W_W20  + (size_t)l * 262144;
        size_t oB1  = (size_t)l * FF;
        size_t oB2  = (size_t)l * DD;
        size_t oG   = (size_t)l * 3 * DD;

        // --- self attention ---
        gemm_mfma_k<2, 1><<<gQKV, blk, 0, stream>>>(xh, xl, Wh, Wl, oQKV,
            nullptr, 0, 0, SAh, SAl, (int)NTOK, 3 * DD, DD, 0, DD, NTOK * DD, flag);
        attn_mfma_k<1><<<attn_blocks, 256, 0, stream>>>(Qh, Ql,
            SAh + NTOK * DD, SAl + NTOK * DD, SAh + 2 * NTOK * DD, SAl + 2 * NTOK * DD,
            Oh, Ol, SS);
        gemm_mfma_k<2, 0><<<gP, blk, 0, stream>>>(Oh, Ol, Wh, Wl, oSAO,
            nullptr, 0, 0, Tb, nullptr, (int)NTOK, DD, DD, 0, 0, 0, flag);
        add_ln_k<<<NTOK, 256, 0, stream>>>(x, Tb, xh, xl, ln_g, oG, ln_b, oG, flag);
        // --- cross attention ---
        gemm_mfma_k<2, 1><<<gP, blk, 0, stream>>>(xh, xl, Wh, Wl, oCAQ,
            nullptr, 0, 0, Qh, Ql, (int)NTOK, DD, DD, 0, 0, 0, flag);
        gemm_mfma_k<1, 1><<<gCKV, blk, 0, stream>>>(encoded, nullptr, Wh, Wl, oCKV,
            nullptr, 0, 0, CKh, CKl, (int)NENC, 2 * DD, DD, 0, DD, NENC * DD, flag);
        attn_mfma_k<0><<<attn_blocks, 256, 0, stream>>>(Qh, Ql,
            CKh, CKl, CKh + NENC * DD, CKl + NENC * DD, Oh, Ol, MM);
        gemm_mfma_k<2, 0><<<gP, blk, 0, stream>>>(Oh, Ol, Wh, Wl, oCAO,
            nullptr, 0, 0, Tb, nullptr, (int)NTOK, DD, DD, 0, 0, 0, flag);
        add_ln_k<<<NTOK, 256, 0, stream>>>(x, Tb, xh, xl, ln_g, oG + DD, ln_b, oG + DD, flag);
        // --- FFN ---
        gemm_mfma_k<2, 1><<<gW1, blk, 0, stream>>>(xh, xl, Wh, Wl, oW1,
            ffn_b1, oB1, 1, Hh, Hl, (int)NTOK, FF, DD, 1, 0, 0, flag);
        gemm_mfma_k<2, 0><<<gP, blk, 0, stream>>>(Hh, Hl, Wh, Wl, oW2,
            ffn_b2, oB2, 1, Tb, nullptr, (int)NTOK, DD, FF, 0, 0, 0, flag);
        add_ln_k<<<NTOK, 256, 0, stream>>>(x, Tb, xh, xl, ln_g, oG + 2 * DD, ln_b, oG + 2 * DD, flag);
    }
    // final norm + shared-embedding logits
    add_ln_k<<<NTOK, 256, 0, stream>>>(x, nullptr, xh, xl, fin_g, 0, fin_b, 0, flag);
    gemm_mfma_k<2, 2><<<gOut, blk, 0, stream>>>(xh, xl, Wh, Wl, W_EMB0,
        (const char*)output_bias, 0, 1, d_out, nullptr, (int)NTOK, VV, DD, 0, 0, 0, flag);
}

// Round 7
// 1896.127 us; speedup vs baseline: 1.2319x; 1.1380x over previous
//
#include <hip/hip_runtime.h>
#include <hip/hip_bf16.h>

#define DD 256
#define HH 8
#define DH 32
#define SS 512
#define MM 1024
#define BB 16
#define FF 1024
#define LL 6
#define VV 3000

typedef __bf16 bf16x8 __attribute__((ext_vector_type(8)));
typedef float  f32x4  __attribute__((ext_vector_type(4)));

// Wt layout offsets (elements). All matrices stored [N][K] bf16 hi/lo pairs.
#define W_QKV0 0u
#define W_SAO0 1179648u
#define W_CAQ0 1572864u
#define W_CKV0 1966080u
#define W_CAO0 2752512u
#define W_W10  3145728u
#define W_W20  4718592u
#define W_EMB0 6291456u
#define W_TOT  7061504u   // 6291456 + 3008*256

// Mixed-dtype load: bf==1 -> bf16, bf==0 -> fp32.
__device__ __forceinline__ float ldx(const void* p, size_t i, int bf) {
    if (bf) return __bfloat162float(((const __hip_bfloat16*)p)[i]);
    return ((const float*)p)[i];
}

// fp32 -> bf16 hi/lo split: v = hi + lo + O(2^-17 * v)
__device__ __forceinline__ void split1(float v, __bf16& h, __bf16& l) {
    h = (__bf16)v;
    l = (__bf16)(v - (float)h);
}

// LDS index with XOR chunk swizzle on a [64 rows][64 el] bf16 tile (128-B
// rows, 8 chunks of 16B). chunk c at row r lives at c ^ (r&7).
__device__ __forceinline__ int swzi(int row, int c) {
    return row * 64 + ((c ^ (row & 7)) << 3);
}

// dtype detector: writes 1 if buffer is bf16, 0 if fp32.
__global__ void detect_k(const unsigned int* __restrict__ w, int* __restrict__ flag) {
    int t = threadIdx.x;
    unsigned int v = w[t];
    int ok = 1;
#pragma unroll
    for (int h = 0; h < 2; ++h) {
        unsigned int hw = (v >> (16 * h)) & 0xFFFFu;
        unsigned int e = (hw >> 7) & 0xFFu;
        if (!((e >= 90u && e <= 140u) || (hw & 0x7FFFu) == 0u)) ok = 0;
    }
    __shared__ int allok;
    if (t == 0) allok = 1;
    __syncthreads();
    if (!ok) atomicAnd(&allok, 0);
    __syncthreads();
    if (t == 0) *flag = allok;
}

// One-time: transpose+split all layer weights into [N][K] bf16 hi/lo pairs.
__global__ __launch_bounds__(256)
void wsplit_k(const void* __restrict__ sa_qkv, const void* __restrict__ sa_o,
              const void* __restrict__ ca_q, const void* __restrict__ ca_kv,
              const void* __restrict__ ca_o, const void* __restrict__ w1,
              const void* __restrict__ w2,
              __bf16* __restrict__ Wh, __bf16* __restrict__ Wl,
              const int* __restrict__ flagp) {
    int bfw = *flagp;
    __shared__ float tile[64][65];
    int blk = blockIdx.x;
    int l = blk >> 8, r = blk & 255;
    const void* src; size_t soff, doff; int K_, N_, ti;
    if (r < 48)       { src = sa_qkv; int j = r >> 4; ti = r & 15;
                        soff = (size_t)(l * 3 + j) * 65536; doff = W_QKV0 + soff; K_ = 256; N_ = 256; }
    else if (r < 64)  { src = sa_o;  ti = r - 48;  soff = (size_t)l * 65536; doff = W_SAO0 + soff; K_ = 256; N_ = 256; }
    else if (r < 80)  { src = ca_q;  ti = r - 64;  soff = (size_t)l * 65536; doff = W_CAQ0 + soff; K_ = 256; N_ = 256; }
    else if (r < 112) { src = ca_kv; int j = (r - 80) >> 4; ti = (r - 80) & 15;
                        soff = (size_t)(l * 2 + j) * 65536; doff = W_CKV0 + soff; K_ = 256; N_ = 256; }
    else if (r < 128) { src = ca_o;  ti = r - 112; soff = (size_t)l * 65536; doff = W_CAO0 + soff; K_ = 256; N_ = 256; }
    else if (r < 192) { src = w1;    ti = r - 128; soff = (size_t)l * 262144; doff = W_W10 + soff; K_ = 256; N_ = 1024; }
    else              { src = w2;    ti = r - 192; soff = (size_t)l * 262144; doff = W_W20 + soff; K_ = 1024; N_ = 256; }
    int ntil = N_ >> 6;
    int kt = ti / ntil, nt = ti % ntil;
    int k0 = kt * 64, n0 = nt * 64;
    int t = threadIdx.x;
#pragma unroll
    for (int rr = 0; rr < 16; ++rr) {
        int kk = rr * 4 + (t >> 6), nn = t & 63;
        tile[kk][nn] = ldx(src, soff + (size_t)(k0 + kk) * N_ + n0 + nn, bfw);
    }
    __syncthreads();
#pragma unroll
    for (int rr = 0; rr < 16; ++rr) {
        int nn = rr * 4 + (t >> 6), kk = t & 63;
        float v = tile[kk][nn];
        size_t o = doff + (size_t)(n0 + nn) * K_ + k0 + kk;
        split1(v, Wh[o], Wl[o]);
    }
}

// One-time: split shared embedding [V][D]; pad rows V..3007 with 0.
__global__ void embsplit_k(const void* __restrict__ emb,
                           __bf16* __restrict__ Wh, __bf16* __restrict__ Wl,
                           const int* __restrict__ flagp) {
    int bfw = *flagp;
    int row = blockIdx.x;           // 0..3007
    int d = threadIdx.x;
    float v = (row < VV) ? ldx(emb, (size_t)row * DD + d, bfw) : 0.f;
    size_t o = W_EMB0 + (size_t)row * DD + d;
    split1(v, Wh[o], Wl[o]);
}

// x = input_embed[seq] + pos_embed ; also writes hi/lo split of x
__global__ void embed_k(const int* __restrict__ seq,
                        const void* __restrict__ emb,
                        const void* __restrict__ pos,
                        float* __restrict__ x,
                        __bf16* __restrict__ xh,
                        __bf16* __restrict__ xl,
                        const int* __restrict__ flagp) {
    int bf = *flagp;
    int row = blockIdx.x;
    int d = threadIdx.x;
    int s = row & (SS - 1);
    int b = row >> 9;
    int tok = seq[b * SS + s];
    float v = ldx(emb, (size_t)tok * DD + d, bf) + ldx(pos, (size_t)s * DD + d, bf);
    size_t idx = (size_t)row * DD + d;
    x[idx] = v;
    split1(v, xh[idx], xl[idx]);
}

// ---------------------------------------------------------------------------
// Split-bf16 MFMA GEMM.  C[M,N] = A[M,K] @ B[K,N] (+bias)(+relu)
//   B: pre-split [N][K] bf16 hi/lo pairs at Wh/Wl + boff.
//   AMODE 1: A is flag-dtype global, split in-kernel; 2: pre-split pair.
//   OUTMODE 0: fp32 C; 1: split pair C/C2; 2: flag-dtype store, col<N guard;
//   OUTMODE 3: bf16 hi-only store (attention inputs).
//   nsplit>0: B rows stacked; C per-mat addressed, advanced by mat*cstride.
// Tile BM=64 BN=64 BK=32, 128 thr = 2 waves, wave 32x64 (2x4 frags 16x16x32).
// LDS: PACKED hi/lo tiles [64][64] (cols 0..31 hi, 32..63 lo), swzi swizzle.
// XCD-chunked bijective block swizzle (m204) for L2 locality.
// ---------------------------------------------------------------------------
template <int AMODE, int OUTMODE>
__global__ __launch_bounds__(128, 3)
void gemm_mfma_k(const void* __restrict__ A, const void* __restrict__ Al_,
                 const __bf16* __restrict__ Wh, const __bf16* __restrict__ Wl, size_t boff,
                 const char* __restrict__ biasbase, size_t biasoff, int hasbias,
                 void* __restrict__ C, void* __restrict__ C2,
                 int M, int N, int K, int relu,
                 int nsplit, size_t cstride,
                 const int* __restrict__ flagp) {
    int bfw = *flagp;
    const __bf16* Bh_g = Wh + boff;
    const __bf16* Bl_g = Wl + boff;
    int t = threadIdx.x;
    int lane = t & 63;
    int wv = t >> 6;

    // XCD-chunked bijective swizzle (m204), ids m-major.
    int gx = gridDim.x;
    int nwg = gx * gridDim.y;
    int id = blockIdx.y * gx + blockIdx.x;
    int q = nwg >> 3, r = nwg & 7;
    int xcd = id & 7, sub = id >> 3;
    int nid = (xcd < r ? xcd * (q + 1) : r * (q + 1) + (xcd - r) * q) + sub;
    int nB0 = (nid % gx) * 64;       // GLOBAL n for B loads (stacked rows)
    int m0  = (nid / gx) * 64;

    int n0 = nB0;                    // within-mat n for C addressing
    int ldc = N;
    float* Cf = (float*)C;
    __bf16* Ch = (__bf16*)C;
    __bf16* Cl2 = (__bf16*)C2;
    if (nsplit) {
        int mat = n0 / nsplit;
        n0 -= mat * nsplit;
        Cf  += (size_t)mat * cstride;
        Ch  += (size_t)mat * cstride;
        Cl2 += (size_t)mat * cstride;
        ldc = nsplit;
    }

    __shared__ __align__(16) __bf16 Ahl[4096];   // [64][64] packed hi|lo
    __shared__ __align__(16) __bf16 Bhl[4096];

    f32x4 acc[2][4] = {};
    int fr = lane & 15;
    int fg = lane >> 4;
    int t_alo = !(AMODE == 1 && bfw);
    int t_blo = !bfw;

    int srow = t >> 1;               // staging row 0..63
    int h2 = t & 1;                  // k-half: elements h2*16 .. h2*16+15

    bf16x8 pah[2], pal[2], pbh[2], pbl[2];

    auto loadA = [&](int k0) {
        size_t g = (size_t)(m0 + srow) * K + k0 + h2 * 16;
        if (AMODE == 2) {
            pah[0] = *(const bf16x8*)((const __bf16*)A + g);
            pah[1] = *(const bf16x8*)((const __bf16*)A + g + 8);
            pal[0] = *(const bf16x8*)((const __bf16*)Al_ + g);
            pal[1] = *(const bf16x8*)((const __bf16*)Al_ + g + 8);
        } else if (bfw) {
            pah[0] = *(const bf16x8*)((const __hip_bfloat16*)A + g);
            pah[1] = *(const bf16x8*)((const __hip_bfloat16*)A + g + 8);
        } else {
#pragma unroll
            for (int c = 0; c < 2; ++c) {
                float4 f1 = *(const float4*)((const float*)A + g + c * 8);
                float4 f2 = *(const float4*)((const float*)A + g + c * 8 + 4);
                float vv[8] = {f1.x, f1.y, f1.z, f1.w, f2.x, f2.y, f2.z, f2.w};
                bf16x8 hv, lv;
#pragma unroll
                for (int e = 0; e < 8; ++e) { __bf16 h, l; split1(vv[e], h, l); hv[e] = h; lv[e] = l; }
                pah[c] = hv; pal[c] = lv;
            }
        }
    };
    auto loadB = [&](int k0) {
        size_t g = (size_t)(nB0 + srow) * K + k0 + h2 * 16;
        pbh[0] = *(const bf16x8*)(Bh_g + g);
        pbh[1] = *(const bf16x8*)(Bh_g + g + 8);
        pbl[0] = *(const bf16x8*)(Bl_g + g);
        pbl[1] = *(const bf16x8*)(Bl_g + g + 8);
    };
    auto writeLDS = [&]() {
#pragma unroll
        for (int j = 0; j < 2; ++j) {
            int ch = h2 * 2 + j;                       // hi chunk 0..3
            *(bf16x8*)&Ahl[swzi(srow, ch)] = pah[j];
            *(bf16x8*)&Bhl[swzi(srow, ch)] = pbh[j];
            *(bf16x8*)&Bhl[swzi(srow, 4 + ch)] = pbl[j];
            if (!(AMODE == 1 && bfw))
                *(bf16x8*)&Ahl[swzi(srow, 4 + ch)] = pal[j];
        }
    };

    loadA(0); loadB(0);
    for (int k0 = 0; k0 < K; k0 += 32) {
        writeLDS();
        __syncthreads();
        if (k0 + 32 < K) { loadA(k0 + 32); loadB(k0 + 32); }

        bf16x8 afh[2], afl[2], bgh[4], bgl[4];
#pragma unroll
        for (int f = 0; f < 2; ++f) {
            int row = wv * 32 + f * 16 + fr;
            afh[f] = *(const bf16x8*)&Ahl[swzi(row, fg)];
            afl[f] = *(const bf16x8*)&Ahl[swzi(row, 4 + fg)];
        }
#pragma unroll
        for (int f = 0; f < 4; ++f) {
            int row = f * 16 + fr;
            bgh[f] = *(const bf16x8*)&Bhl[swzi(row, fg)];
            bgl[f] = *(const bf16x8*)&Bhl[swzi(row, 4 + fg)];
        }
#pragma unroll
        for (int mf = 0; mf < 2; ++mf)
#pragma unroll
            for (int nf = 0; nf < 4; ++nf) {
                acc[mf][nf] = __builtin_amdgcn_mfma_f32_16x16x32_bf16(afh[mf], bgh[nf], acc[mf][nf], 0, 0, 0);
                if (t_alo)
                    acc[mf][nf] = __builtin_amdgcn_mfma_f32_16x16x32_bf16(afl[mf], bgh[nf], acc[mf][nf], 0, 0, 0);
                if (t_blo)
                    acc[mf][nf] = __builtin_amdgcn_mfma_f32_16x16x32_bf16(afh[mf], bgl[nf], acc[mf][nf], 0, 0, 0);
            }
        __syncthreads();
    }

    const char* biasp = biasbase + biasoff * (bfw ? 2 : 4);
#pragma unroll
    for (int mf = 0; mf < 2; ++mf)
#pragma unroll
        for (int nf = 0; nf < 4; ++nf)
#pragma unroll
            for (int r2 = 0; r2 < 4; ++r2) {
                int row = m0 + wv * 32 + mf * 16 + fg * 4 + r2;
                int col = n0 + nf * 16 + fr;
                float v = acc[mf][nf][r2];
                if (OUTMODE == 2) {
                    if (col < N) {
                        v += ldx(biasp, col, bfw);
                        size_t oi = (size_t)row * N + col;
                        if (bfw) ((__hip_bfloat16*)C)[oi] = __float2bfloat16(v);
                        else     ((float*)C)[oi] = v;
                    }
                } else {
                    if (hasbias) v += ldx(biasp, col, bfw);
                    if (relu) v = fmaxf(v, 0.f);
                    size_t oi = (size_t)row * ldc + col;
                    if (OUTMODE == 1) {
                        __bf16 h, l; split1(v, h, l);
                        Ch[oi]  = h;
                        Cl2[oi] = l;
                    } else if (OUTMODE == 3) {
                        Ch[oi] = (__bf16)v;
                    } else {
                        Cf[oi] = v;
                    }
                }
            }
}

// ---------------------------------------------------------------------------
// Plain-bf16 MFMA flash attention. Block = (b,h,64 q) -> 1024 blocks, 4
// waves; wave owns 16 q-rows. Q/K/V single bf16 (numerics: scores ~0.1,
// bf16 error ~4e-4 -> negligible vs 0.09 absmax budget). O written as
// hi/lo pair from fp32 accumulators for the downstream o-proj GEMM.
// V transposed in LDS with stride 66 (dword stride 33 == 1 mod 32):
// scalar transpose writes hit all 32 banks (was 4-way at stride 72).
// ---------------------------------------------------------------------------
template <int CAUSAL>
__global__ __launch_bounds__(256)
void attn_mfma_k(const __bf16* __restrict__ Qg,
                 const __bf16* __restrict__ Kg,
                 const __bf16* __restrict__ Vg,
                 __bf16* __restrict__ Oh, __bf16* __restrict__ Ol,
                 int Sk) {
    __shared__ __align__(16) __bf16 Ks[64][40];
    __shared__ __align__(16) __bf16 Vt[32][66];
    __shared__ __align__(16) __bf16 Ps[4][16][72];

    int t = threadIdx.x;
    int lane = t & 63;
    int w = t >> 6;
    int l15 = lane & 15;
    int g = lane >> 4;

    int blk = blockIdx.x;           // (b*HH + h)*8 + qt
    int qt = blk & 7;
    int h  = (blk >> 3) & (HH - 1);
    int b  = blk >> 6;
    int q0 = qt * 64;

    const float scale = 0.17677669529663689f;  // 1/sqrt(32)

    // Q fragment: row = l15, k(d) = g*8+e; pre-scale in fp32, round to bf16.
    bf16x8 q_;
    {
        size_t qi = ((size_t)(b * SS + q0 + w * 16 + l15)) * DD + h * 32 + g * 8;
        bf16x8 q8 = *(const bf16x8*)(Qg + qi);
#pragma unroll
        for (int j = 0; j < 8; ++j) q_[j] = (__bf16)((float)q8[j] * scale);
    }

    f32x4 oacc[2] = {};
    float m_r[4] = {-1e30f, -1e30f, -1e30f, -1e30f};
    float l_r[4] = {0.f, 0.f, 0.f, 0.f};

    int ntiles = CAUSAL ? (qt + 1) : (Sk >> 6);

    for (int tt = 0; tt < ntiles; ++tt) {
        int j0 = tt * 64;
        // stage K rows (b128 copies) + V transposed (scalar, stride 66)
        {
            int row = t >> 2, db = (t & 3) * 8;
            size_t gi = ((size_t)(b * Sk + j0 + row)) * DD + h * 32 + db;
            *(bf16x8*)&Ks[row][db] = *(const bf16x8*)(Kg + gi);
            bf16x8 v8 = *(const bf16x8*)(Vg + gi);
#pragma unroll
            for (int j = 0; j < 8; ++j) Vt[db + j][row] = v8[j];
        }
        __syncthreads();

        // QK^T: S[16q][64k] per wave (4 MFMAs)
        f32x4 s[4] = {};
#pragma unroll
        for (int kt = 0; kt < 4; ++kt) {
            bf16x8 kb = *(const bf16x8*)&Ks[kt * 16 + l15][g * 8];
            s[kt] = __builtin_amdgcn_mfma_f32_16x16x32_bf16(q_, kb, s[kt], 0, 0, 0);
        }

        if (CAUSAL && tt == ntiles - 1) {
            int qa_ = q0 + w * 16 + g * 4;
#pragma unroll
            for (int kt = 0; kt < 4; ++kt)
#pragma unroll
                for (int r = 0; r < 4; ++r)
                    if (j0 + kt * 16 + l15 > qa_ + r) s[kt][r] = -1e30f;
        }

        // online softmax (per q-row r); P -> LDS bf16
        float al_r[4];
#pragma unroll
        for (int r = 0; r < 4; ++r) {
            float mx = fmaxf(fmaxf(s[0][r], s[1][r]), fmaxf(s[2][r], s[3][r]));
#pragma unroll
            for (int off = 1; off < 16; off <<= 1) mx = fmaxf(mx, __shfl_xor(mx, off));
            float mnew = fmaxf(m_r[r], mx);
            al_r[r] = __expf(m_r[r] - mnew);
            float ps = 0.f;
#pragma unroll
            for (int kt = 0; kt < 4; ++kt) {
                float p = __expf(s[kt][r] - mnew);
                s[kt][r] = p;
                ps += p;
            }
#pragma unroll
            for (int off = 1; off < 16; off <<= 1) ps += __shfl_xor(ps, off);
            l_r[r] = l_r[r] * al_r[r] + ps;
            m_r[r] = mnew;
        }
#pragma unroll
        for (int dt = 0; dt < 2; ++dt)
#pragma unroll
            for (int r = 0; r < 4; ++r) oacc[dt][r] *= al_r[r];
#pragma unroll
        for (int kt = 0; kt < 4; ++kt)
#pragma unroll
            for (int r = 0; r < 4; ++r)
                Ps[w][g * 4 + r][kt * 16 + l15] = (__bf16)s[kt][r];
        __syncthreads();

        // PV: O[16q][32d] += P @ V  (4 MFMAs)
#pragma unroll
        for (int kc = 0; kc < 2; ++kc) {
            bf16x8 pa = *(const bf16x8*)&Ps[w][l15][kc * 32 + g * 8];
#pragma unroll
            for (int dt = 0; dt < 2; ++dt) {
                bf16x8 vb = *(const bf16x8*)&Vt[dt * 16 + l15][kc * 32 + g * 8];
                oacc[dt] = __builtin_amdgcn_mfma_f32_16x16x32_bf16(pa, vb, oacc[dt], 0, 0, 0);
            }
        }
        __syncthreads();
    }

    float inv[4];
#pragma unroll
    for (int r = 0; r < 4; ++r) inv[r] = 1.f / l_r[r];
#pragma unroll
    for (int dt = 0; dt < 2; ++dt)
#pragma unroll
        for (int r = 0; r < 4; ++r) {
            float v = oacc[dt][r] * inv[r];
            size_t oi = ((size_t)(b * SS + q0 + w * 16 + g * 4 + r)) * DD + h * 32 + dt * 16 + l15;
            __bf16 hh, ll; split1(v, hh, ll);
            Oh[oi] = hh;
            Ol[oi] = ll;
        }
}

// x = LN(x + h); also writes hi/lo split of new x.
__global__ void add_ln_k(float* __restrict__ x,
                         const float* __restrict__ hbuf,
                         __bf16* __restrict__ xh,
                         __bf16* __restrict__ xl,
                         const char* __restrict__ gbase, size_t goff,
                         const char* __restrict__ bbase, size_t boff,
                         const int* __restrict__ flagp) {
    int bf = *flagp;
    const void* g = gbase + goff * (bf ? 2 : 4);
    const void* bb = bbase + boff * (bf ? 2 : 4);
    int row = blockIdx.x;
    int d = threadIdx.x;
    float v = x[(size_t)row * DD + d];
    if (hbuf) v += hbuf[(size_t)row * DD + d];
    float s = v, s2 = v * v;
#pragma unroll
    for (int off = 32; off > 0; off >>= 1) {
        s += __shfl_down(s, off);
        s2 += __shfl_down(s2, off);
    }
    __shared__ float sh[8];
    int w = d >> 6;
    if ((d & 63) == 0) { sh[w] = s; sh[4 + w] = s2; }
    __syncthreads();
    if (d == 0) {
        sh[0] = sh[0] + sh[1] + sh[2] + sh[3];
        sh[4] = sh[4] + sh[5] + sh[6] + sh[7];
    }
    __syncthreads();
    float mu = sh[0] * (1.f / DD);
    float var = fmaxf(sh[4] * (1.f / DD) - mu * mu, 0.f);
    float inv = rsqrtf(var + 1e-5f);
    float o = (v - mu) * inv * ldx(g, d, bf) + ldx(bb, d, bf);
    size_t idx = (size_t)row * DD + d;
    x[idx] = o;
    split1(o, xh[idx], xl[idx]);
}

extern "C" void kernel_launch(void* const* d_in, const int* in_sizes, int n_in,
                              void* d_out, int out_size, void* d_ws, size_t ws_size,
                              hipStream_t stream) {
    const void* encoded     = d_in[0];
    const int*  seq         = (const int*)d_in[1];
    const void* input_embed = d_in[2];
    const void* pos_embed   = d_in[3];
    const void* output_bias = d_in[4];
    const void* sa_qkv      = d_in[5];
    const void* sa_o        = d_in[6];
    const void* ca_q        = d_in[7];
    const void* ca_kv       = d_in[8];
    const void* ca_o        = d_in[9];
    const void* ffn_w1      = d_in[10];
    const char* ffn_b1      = (const char*)d_in[11];
    const void* ffn_w2      = d_in[12];
    const char* ffn_b2      = (const char*)d_in[13];
    const char* ln_g        = (const char*)d_in[14];
    const char* ln_b        = (const char*)d_in[15];
    const char* fin_g       = (const char*)d_in[16];
    const char* fin_b       = (const char*)d_in[17];

    const size_t NTOK = (size_t)BB * SS;          // 8192
    const size_t NENC = (size_t)BB * MM;          // 16384

    // Workspace layout (~99 MiB)
    char* p = (char*)d_ws;
    int*    flag = (int*)p;            p += 256;
    float*  x    = (float*)p;          p += NTOK * DD * 4;       // 8 MiB
    __bf16* xh   = (__bf16*)p;         p += NTOK * DD * 2;       // 4 MiB
    __bf16* xl   = (__bf16*)p;         p += NTOK * DD * 2;       // 4 MiB
    __bf16* SAh  = (__bf16*)p;         p += 3 * NTOK * DD * 2;   // 12 MiB (Q,K,V self bf16)
    __bf16* SAl  = (__bf16*)p;         p += 3 * NTOK * DD * 2;   // 12 MiB (spare)
    __bf16* CKh  = (__bf16*)p;         p += 2 * NENC * DD * 2;   // 16 MiB (cross K,V / FFN H hi)
    __bf16* CKl  = (__bf16*)p;         p += 2 * NENC * DD * 2;   // 16 MiB (FFN H lo)
    __bf16* Wh   = (__bf16*)p;         p += (size_t)W_TOT * 2;   // 13.5 MiB
    __bf16* Wl   = (__bf16*)p;         p += (size_t)W_TOT * 2;   // 13.5 MiB
    // aliases (lifetimes verified):
    float*  Tb = (float*)(SAh + NTOK * DD);   // 8 MiB in dead self-K/V space
    __bf16* Oh = xh;   __bf16* Ol = xl;       // attn O (xh/xl dead in between)
    __bf16* Hh = CKh;  __bf16* Hl = CKl;      // FFN hidden pairs

    detect_k<<<1, 256, 0, stream>>>((const unsigned int*)input_embed, flag);
    wsplit_k<<<1536, 256, 0, stream>>>(sa_qkv, sa_o, ca_q, ca_kv, ca_o,
                                       ffn_w1, ffn_w2, Wh, Wl, flag);
    embsplit_k<<<3008, 256, 0, stream>>>(input_embed, Wh, Wl, flag);
    embed_k<<<NTOK, 256, 0, stream>>>(seq, input_embed, pos_embed, x, xh, xl, flag);

    dim3 blk(128);
    dim3 gQKV(12, 128);                // N=768 (3 mats), M=8192
    dim3 gP(4, 128);                   // N=256, M=8192
    dim3 gCKV(8, 256);                 // N=512 (2 mats), M=16384
    dim3 gW1(16, 128);                 // N=1024, M=8192
    dim3 gOut(47, 128);                // N=3000 (guarded), M=8192
    int attn_blocks = BB * HH * (SS / 64);   // 1024

    for (int l = 0; l < LL; ++l) {
        size_t oQKV = W_QKV0 + (size_t)l * 3 * 65536;
        size_t oSAO = W_SAO0 + (size_t)l * 65536;
        size_t oCAQ = W_CAQ0 + (size_t)l * 65536;
        size_t oCKV = W_CKV0 + (size_t)l * 2 * 65536;
        size_t oCAO = W_CAO0 + (size_t)l * 65536;
        size_t oW1  = W_W10  + (size_t)l * 262144;
        size_t oW2  = W_W20  + (size_t)l * 262144;
        size_t oB1  = (size_t)l * FF;
        size_t oB2  = (size_t)l * DD;
        size_t oG   = (size_t)l * 3 * DD;

        // --- self attention (Q,K,V single bf16 at SAh + m*NTOK*DD) ---
        gemm_mfma_k<2, 3><<<gQKV, blk, 0, stream>>>(xh, xl, Wh, Wl, oQKV,
            nullptr, 0, 0, SAh, nullptr, (int)NTOK, 3 * DD, DD, 0, DD, NTOK * DD, flag);
        attn_mfma_k<1><<<attn_blocks, 256, 0, stream>>>(SAh,
            SAh + NTOK * DD, SAh + 2 * NTOK * DD, Oh, Ol, SS);
        gemm_mfma_k<2, 0><<<gP, blk, 0, stream>>>(Oh, Ol, Wh, Wl, oSAO,
            nullptr, 0, 0, Tb, nullptr, (int)NTOK, DD, DD, 0, 0, 0, flag);
        add_ln_k<<<NTOK, 256, 0, stream>>>(x, Tb, xh, xl, ln_g, oG, ln_b, oG, flag);
        // --- cross attention ---
        gemm_mfma_k<2, 3><<<gP, blk, 0, stream>>>(xh, xl, Wh, Wl, oCAQ,
            nullptr, 0, 0, SAh, nullptr, (int)NTOK, DD, DD, 0, 0, 0, flag);
        gemm_mfma_k<1, 3><<<gCKV, blk, 0, stream>>>(encoded, nullptr, Wh, Wl, oCKV,
            nullptr, 0, 0, CKh, nullptr, (int)NENC, 2 * DD, DD, 0, DD, NENC * DD, flag);
        attn_mfma_k<0><<<attn_blocks, 256, 0, stream>>>(SAh,
            CKh, CKh + NENC * DD, Oh, Ol, MM);
        gemm_mfma_k<2, 0><<<gP, blk, 0, stream>>>(Oh, Ol, Wh, Wl, oCAO,
            nullptr, 0, 0, Tb, nullptr, (int)NTOK, DD, DD, 0, 0, 0, flag);
        add_ln_k<<<NTOK, 256, 0, stream>>>(x, Tb, xh, xl, ln_g, oG + DD, ln_b, oG + DD, flag);
        // --- FFN ---
        gemm_mfma_k<2, 1><<<gW1, blk, 0, stream>>>(xh, xl, Wh, Wl, oW1,
            ffn_b1, oB1, 1, Hh, Hl, (int)NTOK, FF, DD, 1, 0, 0, flag);
        gemm_mfma_k<2, 0><<<gP, blk, 0, stream>>>(Hh, Hl, Wh, Wl, oW2,
            ffn_b2, oB2, 1, Tb, nullptr, (int)NTOK, DD, FF, 0, 0, 0, flag);
        add_ln_k<<<NTOK, 256, 0, stream>>>(x, Tb, xh, xl, ln_g, oG + 2 * DD, ln_b, oG + 2 * DD, flag);
    }
    // final norm + shared-embedding logits
    add_ln_k<<<NTOK, 256, 0, stream>>>(x, nullptr, xh, xl, fin_g, 0, fin_b, 0, flag);
    gemm_mfma_k<2, 2><<<gOut, blk, 0, stream>>>(xh, xl, Wh, Wl, W_EMB0,
        (const char*)output_bias, 0, 1, d_out, nullptr, (int)NTOK, VV, DD, 0, 0, 0, flag);
}

// Round 8
// 1711.393 us; speedup vs baseline: 1.3649x; 1.1079x over previous
//
#include <hip/hip_runtime.h>
#include <hip/hip_bf16.h>

#define DD 256
#define HH 8
#define DH 32
#define SS 512
#define MM 1024
#define BB 16
#define FF 1024
#define LL 6
#define VV 3000

typedef __bf16 bf16x8 __attribute__((ext_vector_type(8)));
typedef float  f32x4  __attribute__((ext_vector_type(4)));

// Wt layout offsets (elements). All matrices stored [N][K] bf16 hi/lo pairs.
#define W_QKV0 0u
#define W_SAO0 1179648u
#define W_CAQ0 1572864u
#define W_CKV0 1966080u
#define W_CAO0 2752512u
#define W_W10  3145728u
#define W_W20  4718592u
#define W_EMB0 6291456u
#define W_TOT  7061504u   // 6291456 + 3008*256

// Mixed-dtype load: bf==1 -> bf16, bf==0 -> fp32.
__device__ __forceinline__ float ldx(const void* p, size_t i, int bf) {
    if (bf) return __bfloat162float(((const __hip_bfloat16*)p)[i]);
    return ((const float*)p)[i];
}

// fp32 -> bf16 hi/lo split: v = hi + lo + O(2^-17 * v)
__device__ __forceinline__ void split1(float v, __bf16& h, __bf16& l) {
    h = (__bf16)v;
    l = (__bf16)(v - (float)h);
}

// LDS index with XOR chunk swizzle on [rows][64 el] bf16 tiles (128-B rows,
// 8 chunks of 16B). chunk c at row r lives at c ^ (r&7).
__device__ __forceinline__ int swzi(int row, int c) {
    return row * 64 + ((c ^ (row & 7)) << 3);
}

// dtype detector: writes 1 if buffer is bf16, 0 if fp32.
__global__ void detect_k(const unsigned int* __restrict__ w, int* __restrict__ flag) {
    int t = threadIdx.x;
    unsigned int v = w[t];
    int ok = 1;
#pragma unroll
    for (int h = 0; h < 2; ++h) {
        unsigned int hw = (v >> (16 * h)) & 0xFFFFu;
        unsigned int e = (hw >> 7) & 0xFFu;
        if (!((e >= 90u && e <= 140u) || (hw & 0x7FFFu) == 0u)) ok = 0;
    }
    __shared__ int allok;
    if (t == 0) allok = 1;
    __syncthreads();
    if (!ok) atomicAnd(&allok, 0);
    __syncthreads();
    if (t == 0) *flag = allok;
}

// One-time: transpose+split all layer weights into [N][K] bf16 hi/lo pairs.
__global__ __launch_bounds__(256)
void wsplit_k(const void* __restrict__ sa_qkv, const void* __restrict__ sa_o,
              const void* __restrict__ ca_q, const void* __restrict__ ca_kv,
              const void* __restrict__ ca_o, const void* __restrict__ w1,
              const void* __restrict__ w2,
              __bf16* __restrict__ Wh, __bf16* __restrict__ Wl,
              const int* __restrict__ flagp) {
    int bfw = *flagp;
    __shared__ float tile[64][65];
    int blk = blockIdx.x;
    int l = blk >> 8, r = blk & 255;
    const void* src; size_t soff, doff; int K_, N_, ti;
    if (r < 48)       { src = sa_qkv; int j = r >> 4; ti = r & 15;
                        soff = (size_t)(l * 3 + j) * 65536; doff = W_QKV0 + soff; K_ = 256; N_ = 256; }
    else if (r < 64)  { src = sa_o;  ti = r - 48;  soff = (size_t)l * 65536; doff = W_SAO0 + soff; K_ = 256; N_ = 256; }
    else if (r < 80)  { src = ca_q;  ti = r - 64;  soff = (size_t)l * 65536; doff = W_CAQ0 + soff; K_ = 256; N_ = 256; }
    else if (r < 112) { src = ca_kv; int j = (r - 80) >> 4; ti = (r - 80) & 15;
                        soff = (size_t)(l * 2 + j) * 65536; doff = W_CKV0 + soff; K_ = 256; N_ = 256; }
    else if (r < 128) { src = ca_o;  ti = r - 112; soff = (size_t)l * 65536; doff = W_CAO0 + soff; K_ = 256; N_ = 256; }
    else if (r < 192) { src = w1;    ti = r - 128; soff = (size_t)l * 262144; doff = W_W10 + soff; K_ = 256; N_ = 1024; }
    else              { src = w2;    ti = r - 192; soff = (size_t)l * 262144; doff = W_W20 + soff; K_ = 1024; N_ = 256; }
    int ntil = N_ >> 6;
    int kt = ti / ntil, nt = ti % ntil;
    int k0 = kt * 64, n0 = nt * 64;
    int t = threadIdx.x;
#pragma unroll
    for (int rr = 0; rr < 16; ++rr) {
        int kk = rr * 4 + (t >> 6), nn = t & 63;
        tile[kk][nn] = ldx(src, soff + (size_t)(k0 + kk) * N_ + n0 + nn, bfw);
    }
    __syncthreads();
#pragma unroll
    for (int rr = 0; rr < 16; ++rr) {
        int nn = rr * 4 + (t >> 6), kk = t & 63;
        float v = tile[kk][nn];
        size_t o = doff + (size_t)(n0 + nn) * K_ + k0 + kk;
        split1(v, Wh[o], Wl[o]);
    }
}

// One-time: split shared embedding [V][D]; pad rows V..3007 with 0.
__global__ void embsplit_k(const void* __restrict__ emb,
                           __bf16* __restrict__ Wh, __bf16* __restrict__ Wl,
                           const int* __restrict__ flagp) {
    int bfw = *flagp;
    int row = blockIdx.x;           // 0..3007
    int d = threadIdx.x;
    float v = (row < VV) ? ldx(emb, (size_t)row * DD + d, bfw) : 0.f;
    size_t o = W_EMB0 + (size_t)row * DD + d;
    split1(v, Wh[o], Wl[o]);
}

// x = input_embed[seq] + pos_embed ; also writes hi/lo split of x
__global__ void embed_k(const int* __restrict__ seq,
                        const void* __restrict__ emb,
                        const void* __restrict__ pos,
                        float* __restrict__ x,
                        __bf16* __restrict__ xh,
                        __bf16* __restrict__ xl,
                        const int* __restrict__ flagp) {
    int bf = *flagp;
    int row = blockIdx.x;
    int d = threadIdx.x;
    int s = row & (SS - 1);
    int b = row >> 9;
    int tok = seq[b * SS + s];
    float v = ldx(emb, (size_t)tok * DD + d, bf) + ldx(pos, (size_t)s * DD + d, bf);
    size_t idx = (size_t)row * DD + d;
    x[idx] = v;
    split1(v, xh[idx], xl[idx]);
}

// ---------------------------------------------------------------------------
// Split-bf16 MFMA GEMM.  C[M,N] = A[M,K] @ B[K,N] (+bias)(+relu)
//   B: pre-split [N][K] bf16 hi/lo pairs at Wh/Wl + boff.
//   AMODE 1: A flag-dtype global, split in-kernel; 2: pre-split pair.
//   OUTMODE 0: fp32 C; 1: split pair C/C2; 2: flag-dtype store, col<N guard;
//             3: bf16 hi-only store.
//   MFR: m-fragments per wave (1 -> BM=32, 2 -> BM=64). BN=64, BK=32.
//   BSPL: 1 -> include Ah*Bl term (full weight precision, logits only);
//         0 -> weights plain bf16 (err ~0.2%/GEMM, fine vs 0.09 budget).
// 128 thr = 2 waves, wave tile (16*MFR)x64. LDS packed hi/lo tiles with swzi
// XOR swizzle. XCD-chunked bijective block swizzle (m204) for L2 locality.
// ---------------------------------------------------------------------------
template <int AMODE, int OUTMODE, int MFR, int BSPL>
__global__ __launch_bounds__(128, 3)
void gemm_mfma_k(const void* __restrict__ A, const void* __restrict__ Al_,
                 const __bf16* __restrict__ Wh, const __bf16* __restrict__ Wl, size_t boff,
                 const char* __restrict__ biasbase, size_t biasoff, int hasbias,
                 void* __restrict__ C, void* __restrict__ C2,
                 int M, int N, int K, int relu,
                 int nsplit, size_t cstride,
                 const int* __restrict__ flagp) {
    const int BM = 32 * MFR;
    int bfw = *flagp;
    const __bf16* Bh_g = Wh + boff;
    const __bf16* Bl_g = Wl + boff;
    int t = threadIdx.x;
    int lane = t & 63;
    int wv = t >> 6;

    // XCD-chunked bijective swizzle (m204), ids m-major.
    int gx = gridDim.x;
    int nwg = gx * gridDim.y;
    int id = blockIdx.y * gx + blockIdx.x;
    int q = nwg >> 3, r = nwg & 7;
    int xcd = id & 7, sub = id >> 3;
    int nid = (xcd < r ? xcd * (q + 1) : r * (q + 1) + (xcd - r) * q) + sub;
    int nB0 = (nid % gx) * 64;       // GLOBAL n for B loads (stacked rows)
    int m0  = (nid / gx) * BM;

    int n0 = nB0;                    // within-mat n for C addressing
    int ldc = N;
    float* Cf = (float*)C;
    __bf16* Ch = (__bf16*)C;
    __bf16* Cl2 = (__bf16*)C2;
    if (nsplit) {
        int mat = n0 / nsplit;
        n0 -= mat * nsplit;
        Cf  += (size_t)mat * cstride;
        Ch  += (size_t)mat * cstride;
        Cl2 += (size_t)mat * cstride;
        ldc = nsplit;
    }

    __shared__ __align__(16) __bf16 Ahl[BM * 64];   // packed hi(0-3)|lo(4-7)
    __shared__ __align__(16) __bf16 Bhl[4096];

    f32x4 acc[MFR][4] = {};
    int fr = lane & 15;
    int fg = lane >> 4;
    int t_alo = !(AMODE == 1 && bfw);
    int t_blo = BSPL && !bfw;

    // staging maps: A: MFR==2 -> row t>>1, 2 chunks at (t&1)*2; MFR==1 ->
    // row t>>2, 1 chunk at t&3. B: row t>>1, hi 2 chunks (+lo if BSPL).
    int arow = (MFR == 2) ? (t >> 1) : (t >> 2);
    int ac0  = (MFR == 2) ? ((t & 1) * 2) : (t & 3);
    int brow = t >> 1;
    int bc0  = (t & 1) * 2;

    bf16x8 pah[2], pal[2], pbh[2], pbl[2];

    auto loadA = [&](int k0) {
#pragma unroll
        for (int j = 0; j < MFR; ++j) {
            size_t g = (size_t)(m0 + arow) * K + k0 + (ac0 + j) * 8;
            if (AMODE == 2) {
                pah[j] = *(const bf16x8*)((const __bf16*)A + g);
                pal[j] = *(const bf16x8*)((const __bf16*)Al_ + g);
            } else if (bfw) {
                pah[j] = *(const bf16x8*)((const __hip_bfloat16*)A + g);
            } else {
                float4 f1 = *(const float4*)((const float*)A + g);
                float4 f2 = *(const float4*)((const float*)A + g + 4);
                float vv[8] = {f1.x, f1.y, f1.z, f1.w, f2.x, f2.y, f2.z, f2.w};
                bf16x8 hv, lv;
#pragma unroll
                for (int e = 0; e < 8; ++e) { __bf16 h, l; split1(vv[e], h, l); hv[e] = h; lv[e] = l; }
                pah[j] = hv; pal[j] = lv;
            }
        }
    };
    auto loadB = [&](int k0) {
#pragma unroll
        for (int j = 0; j < 2; ++j) {
            size_t g = (size_t)(nB0 + brow) * K + k0 + (bc0 + j) * 8;
            pbh[j] = *(const bf16x8*)(Bh_g + g);
            if (BSPL) pbl[j] = *(const bf16x8*)(Bl_g + g);
        }
    };
    auto writeLDS = [&]() {
#pragma unroll
        for (int j = 0; j < MFR; ++j) {
            *(bf16x8*)&Ahl[swzi(arow, ac0 + j)] = pah[j];
            if (!(AMODE == 1 && bfw))
                *(bf16x8*)&Ahl[swzi(arow, 4 + ac0 + j)] = pal[j];
        }
#pragma unroll
        for (int j = 0; j < 2; ++j) {
            *(bf16x8*)&Bhl[swzi(brow, bc0 + j)] = pbh[j];
            if (BSPL) *(bf16x8*)&Bhl[swzi(brow, 4 + bc0 + j)] = pbl[j];
        }
    };

    loadA(0); loadB(0);
    for (int k0 = 0; k0 < K; k0 += 32) {
        writeLDS();
        __syncthreads();
        if (k0 + 32 < K) { loadA(k0 + 32); loadB(k0 + 32); }

        bf16x8 afh[MFR], afl[MFR], bgh[4], bgl[4];
#pragma unroll
        for (int f = 0; f < MFR; ++f) {
            int row = wv * (16 * MFR) + f * 16 + fr;
            afh[f] = *(const bf16x8*)&Ahl[swzi(row, fg)];
            afl[f] = *(const bf16x8*)&Ahl[swzi(row, 4 + fg)];
        }
#pragma unroll
        for (int f = 0; f < 4; ++f) {
            int row = f * 16 + fr;
            bgh[f] = *(const bf16x8*)&Bhl[swzi(row, fg)];
            if (BSPL) bgl[f] = *(const bf16x8*)&Bhl[swzi(row, 4 + fg)];
        }
#pragma unroll
        for (int mf = 0; mf < MFR; ++mf)
#pragma unroll
            for (int nf = 0; nf < 4; ++nf) {
                acc[mf][nf] = __builtin_amdgcn_mfma_f32_16x16x32_bf16(afh[mf], bgh[nf], acc[mf][nf], 0, 0, 0);
                if (t_alo)
                    acc[mf][nf] = __builtin_amdgcn_mfma_f32_16x16x32_bf16(afl[mf], bgh[nf], acc[mf][nf], 0, 0, 0);
                if (BSPL && t_blo)
                    acc[mf][nf] = __builtin_amdgcn_mfma_f32_16x16x32_bf16(afh[mf], bgl[nf], acc[mf][nf], 0, 0, 0);
            }
        __syncthreads();
    }

    const char* biasp = biasbase + biasoff * (bfw ? 2 : 4);
#pragma unroll
    for (int mf = 0; mf < MFR; ++mf)
#pragma unroll
        for (int nf = 0; nf < 4; ++nf)
#pragma unroll
            for (int r2 = 0; r2 < 4; ++r2) {
                int row = m0 + wv * (16 * MFR) + mf * 16 + fg * 4 + r2;
                int col = n0 + nf * 16 + fr;
                float v = acc[mf][nf][r2];
                if (OUTMODE == 2) {
                    if (col < N) {
                        v += ldx(biasp, col, bfw);
                        size_t oi = (size_t)row * N + col;
                        if (bfw) ((__hip_bfloat16*)C)[oi] = __float2bfloat16(v);
                        else     ((float*)C)[oi] = v;
                    }
                } else {
                    if (hasbias) v += ldx(biasp, col, bfw);
                    if (relu) v = fmaxf(v, 0.f);
                    size_t oi = (size_t)row * ldc + col;
                    if (OUTMODE == 1) {
                        __bf16 h, l; split1(v, h, l);
                        Ch[oi]  = h;
                        Cl2[oi] = l;
                    } else if (OUTMODE == 3) {
                        Ch[oi] = (__bf16)v;
                    } else {
                        Cf[oi] = v;
                    }
                }
            }
}

// ---------------------------------------------------------------------------
// Plain-bf16 MFMA flash attention. Block = (b,h,64 q) -> 1024 blocks, 4
// waves; wave owns 16 q-rows. O written as hi/lo pair from fp32 accum.
// V transposed in LDS stride 66 (dword stride 33 == 1 mod 32, conflict-free).
// ---------------------------------------------------------------------------
template <int CAUSAL>
__global__ __launch_bounds__(256)
void attn_mfma_k(const __bf16* __restrict__ Qg,
                 const __bf16* __restrict__ Kg,
                 const __bf16* __restrict__ Vg,
                 __bf16* __restrict__ Oh, __bf16* __restrict__ Ol,
                 int Sk) {
    __shared__ __align__(16) __bf16 Ks[64][40];
    __shared__ __align__(16) __bf16 Vt[32][66];
    __shared__ __align__(16) __bf16 Ps[4][16][72];

    int t = threadIdx.x;
    int lane = t & 63;
    int w = t >> 6;
    int l15 = lane & 15;
    int g = lane >> 4;

    int blk = blockIdx.x;           // (b*HH + h)*8 + qt
    int qt = blk & 7;
    int h  = (blk >> 3) & (HH - 1);
    int b  = blk >> 6;
    int q0 = qt * 64;

    const float scale = 0.17677669529663689f;  // 1/sqrt(32)

    bf16x8 q_;
    {
        size_t qi = ((size_t)(b * SS + q0 + w * 16 + l15)) * DD + h * 32 + g * 8;
        bf16x8 q8 = *(const bf16x8*)(Qg + qi);
#pragma unroll
        for (int j = 0; j < 8; ++j) q_[j] = (__bf16)((float)q8[j] * scale);
    }

    f32x4 oacc[2] = {};
    float m_r[4] = {-1e30f, -1e30f, -1e30f, -1e30f};
    float l_r[4] = {0.f, 0.f, 0.f, 0.f};

    int ntiles = CAUSAL ? (qt + 1) : (Sk >> 6);

    for (int tt = 0; tt < ntiles; ++tt) {
        int j0 = tt * 64;
        {
            int row = t >> 2, db = (t & 3) * 8;
            size_t gi = ((size_t)(b * Sk + j0 + row)) * DD + h * 32 + db;
            *(bf16x8*)&Ks[row][db] = *(const bf16x8*)(Kg + gi);
            bf16x8 v8 = *(const bf16x8*)(Vg + gi);
#pragma unroll
            for (int j = 0; j < 8; ++j) Vt[db + j][row] = v8[j];
        }
        __syncthreads();

        f32x4 s[4] = {};
#pragma unroll
        for (int kt = 0; kt < 4; ++kt) {
            bf16x8 kb = *(const bf16x8*)&Ks[kt * 16 + l15][g * 8];
            s[kt] = __builtin_amdgcn_mfma_f32_16x16x32_bf16(q_, kb, s[kt], 0, 0, 0);
        }

        if (CAUSAL && tt == ntiles - 1) {
            int qa_ = q0 + w * 16 + g * 4;
#pragma unroll
            for (int kt = 0; kt < 4; ++kt)
#pragma unroll
                for (int r = 0; r < 4; ++r)
                    if (j0 + kt * 16 + l15 > qa_ + r) s[kt][r] = -1e30f;
        }

        float al_r[4];
#pragma unroll
        for (int r = 0; r < 4; ++r) {
            float mx = fmaxf(fmaxf(s[0][r], s[1][r]), fmaxf(s[2][r], s[3][r]));
#pragma unroll
            for (int off = 1; off < 16; off <<= 1) mx = fmaxf(mx, __shfl_xor(mx, off));
            float mnew = fmaxf(m_r[r], mx);
            al_r[r] = __expf(m_r[r] - mnew);
            float ps = 0.f;
#pragma unroll
            for (int kt = 0; kt < 4; ++kt) {
                float p = __expf(s[kt][r] - mnew);
                s[kt][r] = p;
                ps += p;
            }
#pragma unroll
            for (int off = 1; off < 16; off <<= 1) ps += __shfl_xor(ps, off);
            l_r[r] = l_r[r] * al_r[r] + ps;
            m_r[r] = mnew;
        }
#pragma unroll
        for (int dt = 0; dt < 2; ++dt)
#pragma unroll
            for (int r = 0; r < 4; ++r) oacc[dt][r] *= al_r[r];
#pragma unroll
        for (int kt = 0; kt < 4; ++kt)
#pragma unroll
            for (int r = 0; r < 4; ++r)
                Ps[w][g * 4 + r][kt * 16 + l15] = (__bf16)s[kt][r];
        __syncthreads();

#pragma unroll
        for (int kc = 0; kc < 2; ++kc) {
            bf16x8 pa = *(const bf16x8*)&Ps[w][l15][kc * 32 + g * 8];
#pragma unroll
            for (int dt = 0; dt < 2; ++dt) {
                bf16x8 vb = *(const bf16x8*)&Vt[dt * 16 + l15][kc * 32 + g * 8];
                oacc[dt] = __builtin_amdgcn_mfma_f32_16x16x32_bf16(pa, vb, oacc[dt], 0, 0, 0);
            }
        }
        __syncthreads();
    }

    float inv[4];
#pragma unroll
    for (int r = 0; r < 4; ++r) inv[r] = 1.f / l_r[r];
#pragma unroll
    for (int dt = 0; dt < 2; ++dt)
#pragma unroll
        for (int r = 0; r < 4; ++r) {
            float v = oacc[dt][r] * inv[r];
            size_t oi = ((size_t)(b * SS + q0 + w * 16 + g * 4 + r)) * DD + h * 32 + dt * 16 + l15;
            __bf16 hh, ll; split1(v, hh, ll);
            Oh[oi] = hh;
            Ol[oi] = ll;
        }
}

// x = LN(x + h); also writes hi/lo split of new x.
__global__ void add_ln_k(float* __restrict__ x,
                         const float* __restrict__ hbuf,
                         __bf16* __restrict__ xh,
                         __bf16* __restrict__ xl,
                         const char* __restrict__ gbase, size_t goff,
                         const char* __restrict__ bbase, size_t boff,
                         const int* __restrict__ flagp) {
    int bf = *flagp;
    const void* g = gbase + goff * (bf ? 2 : 4);
    const void* bb = bbase + boff * (bf ? 2 : 4);
    int row = blockIdx.x;
    int d = threadIdx.x;
    float v = x[(size_t)row * DD + d];
    if (hbuf) v += hbuf[(size_t)row * DD + d];
    float s = v, s2 = v * v;
#pragma unroll
    for (int off = 32; off > 0; off >>= 1) {
        s += __shfl_down(s, off);
        s2 += __shfl_down(s2, off);
    }
    __shared__ float sh[8];
    int w = d >> 6;
    if ((d & 63) == 0) { sh[w] = s; sh[4 + w] = s2; }
    __syncthreads();
    if (d == 0) {
        sh[0] = sh[0] + sh[1] + sh[2] + sh[3];
        sh[4] = sh[4] + sh[5] + sh[6] + sh[7];
    }
    __syncthreads();
    float mu = sh[0] * (1.f / DD);
    float var = fmaxf(sh[4] * (1.f / DD) - mu * mu, 0.f);
    float inv = rsqrtf(var + 1e-5f);
    float o = (v - mu) * inv * ldx(g, d, bf) + ldx(bb, d, bf);
    size_t idx = (size_t)row * DD + d;
    x[idx] = o;
    split1(o, xh[idx], xl[idx]);
}

extern "C" void kernel_launch(void* const* d_in, const int* in_sizes, int n_in,
                              void* d_out, int out_size, void* d_ws, size_t ws_size,
                              hipStream_t stream) {
    const void* encoded     = d_in[0];
    const int*  seq         = (const int*)d_in[1];
    const void* input_embed = d_in[2];
    const void* pos_embed   = d_in[3];
    const void* output_bias = d_in[4];
    const void* sa_qkv      = d_in[5];
    const void* sa_o        = d_in[6];
    const void* ca_q        = d_in[7];
    const void* ca_kv       = d_in[8];
    const void* ca_o        = d_in[9];
    const void* ffn_w1      = d_in[10];
    const char* ffn_b1      = (const char*)d_in[11];
    const void* ffn_w2      = d_in[12];
    const char* ffn_b2      = (const char*)d_in[13];
    const char* ln_g        = (const char*)d_in[14];
    const char* ln_b        = (const char*)d_in[15];
    const char* fin_g       = (const char*)d_in[16];
    const char* fin_b       = (const char*)d_in[17];

    const size_t NTOK = (size_t)BB * SS;          // 8192
    const size_t NENC = (size_t)BB * MM;          // 16384

    // Workspace layout (~99 MiB)
    char* p = (char*)d_ws;
    int*    flag = (int*)p;            p += 256;
    float*  x    = (float*)p;          p += NTOK * DD * 4;       // 8 MiB
    __bf16* xh   = (__bf16*)p;         p += NTOK * DD * 2;       // 4 MiB
    __bf16* xl   = (__bf16*)p;         p += NTOK * DD * 2;       // 4 MiB
    __bf16* SAh  = (__bf16*)p;         p += 3 * NTOK * DD * 2;   // 12 MiB (Q,K,V self bf16)
    __bf16* SAl  = (__bf16*)p;         p += 3 * NTOK * DD * 2;   // 12 MiB (spare / Tb)
    __bf16* CKh  = (__bf16*)p;         p += 2 * NENC * DD * 2;   // 16 MiB (cross K,V / FFN H hi)
    __bf16* CKl  = (__bf16*)p;         p += 2 * NENC * DD * 2;   // 16 MiB (FFN H lo)
    __bf16* Wh   = (__bf16*)p;         p += (size_t)W_TOT * 2;   // 13.5 MiB
    __bf16* Wl   = (__bf16*)p;         p += (size_t)W_TOT * 2;   // 13.5 MiB
    // aliases (lifetimes verified):
    float*  Tb = (float*)(SAh + NTOK * DD);   // 8 MiB in dead self-K/V space
    __bf16* Oh = xh;   __bf16* Ol = xl;       // attn O (xh/xl dead in between)
    __bf16* Hh = CKh;  __bf16* Hl = CKl;      // FFN hidden pairs

    detect_k<<<1, 256, 0, stream>>>((const unsigned int*)input_embed, flag);
    wsplit_k<<<1536, 256, 0, stream>>>(sa_qkv, sa_o, ca_q, ca_kv, ca_o,
                                       ffn_w1, ffn_w2, Wh, Wl, flag);
    embsplit_k<<<3008, 256, 0, stream>>>(input_embed, Wh, Wl, flag);
    embed_k<<<NTOK, 256, 0, stream>>>(seq, input_embed, pos_embed, x, xh, xl, flag);

    dim3 blk(128);
    dim3 gQKV(12, 128);                // N=768 (3 mats), M=8192, BM=64
    dim3 gP(4, 256);                   // N=256, M=8192, BM=32 -> 1024 blocks
    dim3 gCKV(8, 256);                 // N=512 (2 mats), M=16384, BM=64
    dim3 gW1(16, 128);                 // N=1024, M=8192, BM=64
    dim3 gOut(47, 128);                // N=3000 (guarded), M=8192, BM=64
    int attn_blocks = BB * HH * (SS / 64);   // 1024

    for (int l = 0; l < LL; ++l) {
        size_t oQKV = W_QKV0 + (size_t)l * 3 * 65536;
        size_t oSAO = W_SAO0 + (size_t)l * 65536;
        size_t oCAQ = W_CAQ0 + (size_t)l * 65536;
        size_t oCKV = W_CKV0 + (size_t)l * 2 * 65536;
        size_t oCAO = W_CAO0 + (size_t)l * 65536;
        size_t oW1  = W_W10  + (size_t)l * 262144;
        size_t oW2  = W_W20  + (size_t)l * 262144;
        size_t oB1  = (size_t)l * FF;
        size_t oB2  = (size_t)l * DD;
        size_t oG   = (size_t)l * 3 * DD;

        // --- self attention (Q,K,V single bf16 at SAh + m*NTOK*DD) ---
        gemm_mfma_k<2, 3, 2, 0><<<gQKV, blk, 0, stream>>>(xh, xl, Wh, Wl, oQKV,
            nullptr, 0, 0, SAh, nullptr, (int)NTOK, 3 * DD, DD, 0, DD, NTOK * DD, flag);
        attn_mfma_k<1><<<attn_blocks, 256, 0, stream>>>(SAh,
            SAh + NTOK * DD, SAh + 2 * NTOK * DD, Oh, Ol, SS);
        gemm_mfma_k<2, 0, 1, 0><<<gP, blk, 0, stream>>>(Oh, Ol, Wh, Wl, oSAO,
            nullptr, 0, 0, Tb, nullptr, (int)NTOK, DD, DD, 0, 0, 0, flag);
        add_ln_k<<<NTOK, 256, 0, stream>>>(x, Tb, xh, xl, ln_g, oG, ln_b, oG, flag);
        // --- cross attention ---
        gemm_mfma_k<2, 3, 1, 0><<<gP, blk, 0, stream>>>(xh, xl, Wh, Wl, oCAQ,
            nullptr, 0, 0, SAh, nullptr, (int)NTOK, DD, DD, 0, 0, 0, flag);
        gemm_mfma_k<1, 3, 2, 0><<<gCKV, blk, 0, stream>>>(encoded, nullptr, Wh, Wl, oCKV,
            nullptr, 0, 0, CKh, nullptr, (int)NENC, 2 * DD, DD, 0, DD, NENC * DD, flag);
        attn_mfma_k<0><<<attn_blocks, 256, 0, stream>>>(SAh,
            CKh, CKh + NENC * DD, Oh, Ol, MM);
        gemm_mfma_k<2, 0, 1, 0><<<gP, blk, 0, stream>>>(Oh, Ol, Wh, Wl, oCAO,
            nullptr, 0, 0, Tb, nullptr, (int)NTOK, DD, DD, 0, 0, 0, flag);
        add_ln_k<<<NTOK, 256, 0, stream>>>(x, Tb, xh, xl, ln_g, oG + DD, ln_b, oG + DD, flag);
        // --- FFN ---
        gemm_mfma_k<2, 1, 2, 0><<<gW1, blk, 0, stream>>>(xh, xl, Wh, Wl, oW1,
            ffn_b1, oB1, 1, Hh, Hl, (int)NTOK, FF, DD, 1, 0, 0, flag);
        gemm_mfma_k<2, 0, 1, 0><<<gP, blk, 0, stream>>>(Hh, Hl, Wh, Wl, oW2,
            ffn_b2, oB2, 1, Tb, nullptr, (int)NTOK, DD, FF, 0, 0, 0, flag);
        add_ln_k<<<NTOK, 256, 0, stream>>>(x, Tb, xh, xl, ln_g, oG + 2 * DD, ln_b, oG + 2 * DD, flag);
    }
    // final norm + shared-embedding logits (full 3-term precision)
    add_ln_k<<<NTOK, 256, 0, stream>>>(x, nullptr, xh, xl, fin_g, 0, fin_b, 0, flag);
    gemm_mfma_k<2, 2, 2, 1><<<gOut, blk, 0, stream>>>(xh, xl, Wh, Wl, W_EMB0,
        (const char*)output_bias, 0, 1, d_out, nullptr, (int)NTOK, VV, DD, 0, 0, 0, flag);
}